// Round 2
// baseline (1669.905 us; speedup 1.0000x reference)
//
#include <hip/hip_runtime.h>

// ---------------------------------------------------------------------------
// CommNet round 10: make the software pipeline REAL.
//  R9 counters: conv0 VGPR=56 < 84 minimum for the written 3-stage pipeline ->
//  compiler collapsed it (loads sunk to uses, ~latency-bound, MfmaUtil 27).
//  Fixes (conv0): (1) sched_barrier(0)-pinned LOADS/COMP regions so the
//  distance-2 rotating pipeline survives codegen (counted vmcnt, never 0);
//  (2) dy-merge: wave computes both pool y-rows via imm offset:384 on the
//  same A-address -> 12 MFMA / 3 addr-adds per step, pool dy-max in-register;
//  (3) per-lane delta table Dtx[19][64] + 3-deep rotating dlv prefetch kills
//  the 6-VALU cndmask select and its in-region serial dependency.
//  conv1: same pinning + rotating scalar-offset prefetch, structure unchanged.
// Layouts (HW-verified): A[m=lane&15][k=q*8+j], B[n=lane&15][k=q*8+j],
//  D col=lane&15, row=q*4+reg.
// ---------------------------------------------------------------------------

typedef __attribute__((ext_vector_type(8)))  _Float16 f16x8;
typedef __attribute__((ext_vector_type(8), aligned(8))) _Float16 f16x8u; // 8B-aligned 16B load
typedef __attribute__((ext_vector_type(4)))  float f32x4;

__device__ __forceinline__ ushort f2h(float f) {
    union { _Float16 h; ushort u; } v;
    v.h = (_Float16)f;                       // v_cvt_f16_f32, RNE
    return v.u;
}

#define MFMA16(A, B, C) __builtin_amdgcn_mfma_f32_16x16x32_f16(A, B, C, 0, 0, 0)
#define SB() __builtin_amdgcn_sched_barrier(0)

// ---- prep: x [80][4][45^3] fp32 -> hi0 NDHWC padded [80][47][47][48][4] f16
__global__ void pad_input_kernel(const float* __restrict__ x,
                                 ushort* __restrict__ hi)
{
    int t = blockIdx.x * 256 + threadIdx.x;
    const int TOT = 80 * 45 * 45 * 45;
    if (t >= TOT) return;
    int xi = t % 45, r = t / 45;
    int y = r % 45; r /= 45;
    int z = r % 45; int n = r / 45;
    int ib = ((n * 4) * 91125) + z * 2025 + y * 45 + xi;
    int ob = (((n * 47 + z + 1) * 47 + y + 1) * 48 + xi + 1) * 4;
    ushort h4[4];
    #pragma unroll
    for (int ic = 0; ic < 4; ++ic) {
        float v = x[ib + ic * 91125] * (1.f / 255.f);
        h4[ic] = f2h(v);
    }
    *(ushort4*)(hi + ob) = *(ushort4*)h4;
}

// ---- pack conv0 weights [32][4][5][5][5] -> Bp0[19 s][2 ot][64 lane][8 j] f16
// k = ((kz*5+ky)*6+kx)*4 + ic  (kx in [0,6), kx==5 zero; K=600, 19 steps = 608)
// Dtx: per-lane delta table [19][64] (delta depends on (s, q=lane>>4) only).
__global__ void pack_w0(const float* __restrict__ w, ushort* __restrict__ Bp,
                        int* __restrict__ Dtx)
{
    int t = blockIdx.x * 256 + threadIdx.x;
    if (t < 19 * 2 * 64 * 8) {
        int j = t & 7, l = (t >> 3) & 63, ot = (t >> 9) & 1, s = t >> 10;
        int oc = ot * 16 + (l & 15);
        int k = 32 * s + ((l >> 4) << 3) + j;
        float v = 0.f;
        if (k < 600) {
            int ic = k & 3, t6 = k >> 2;
            int kx = t6 % 6, q = t6 / 6, ky = q % 5, kz = q / 5;
            if (kx < 5) v = w[(oc * 4 + ic) * 125 + kz * 25 + ky * 5 + kx];
        }
        Bp[t] = f2h(v);
    }
    if (t < 19 * 64) {
        int s = t >> 6, q = (t >> 4) & 3;
        int k = 32 * s + 8 * q;
        int d = 0;
        if (k < 600) {
            int t6 = k >> 2;
            int kx = t6 % 6, qq = t6 / 6;
            d = (((qq / 5) * 47 + (qq % 5)) * 48 + kx) * 4;          // x-unit=4
        }
        Dtx[t] = d;
    }
}

// ---- pack conv1 weights [32][32][5][5][5] -> Bp1[126 s][2 ot][64][8] f16
// step s = tap (125 real, 1 zero pad), k = s*32 + ic
__global__ void pack_w1(const float* __restrict__ w, ushort* __restrict__ Bp,
                        int* __restrict__ Dt)
{
    int t = blockIdx.x * 256 + threadIdx.x;
    if (t < 126 * 2 * 64 * 8) {
        int j = t & 7, l = (t >> 3) & 63, ot = (t >> 9) & 1, s = t >> 10;
        int oc = ot * 16 + (l & 15);
        int ic = ((l >> 4) << 3) + j;
        Bp[t] = (s < 125) ? f2h(w[(oc * 32 + ic) * 125 + s]) : (ushort)0;
    }
    if (t < 126) {
        if (t < 125) {
            int kz = t / 25, ky = (t / 5) % 5, kx = t % 5;
            Dt[t] = ((kz * 23 + ky) * 24 + kx) * 32;                 // x-unit=32
        } else Dt[t] = 0;
    }
}

// ---- conv0 MFMA: hi0 [80][47][47][48][4] f16 -> hi1 [80][23][23][24][32] f16
// block = (pz, pyg) covering py = 2*pyg + {0,1}; wave w: dz=w>>1, pyl=w&1.
// Each wave computes BOTH dy rows (A via offset:384), dy-max in-register.
__global__ __launch_bounds__(256, 3)
void conv0_mfma(const ushort* __restrict__ hi0,
                const ushort* __restrict__ Bp, const int* __restrict__ Dtx,
                const float* __restrict__ bias, const float* __restrict__ slope,
                ushort* __restrict__ hi1)
{
    const int n   = blockIdx.z;
    const int pz  = blockIdx.x / 11, pyg = blockIdx.x % 11;
    const int tid = threadIdx.x, lane = tid & 63, w = tid >> 6;
    const int dz  = w >> 1, pyl = w & 1;
    const int py  = 2 * pyg + pyl;            // may be 21 (invalid, pyg==10)
    const int l15 = lane & 15, q = lane >> 4;

    __shared__ float pool[2][2][21][32];      // [dz][pyl][px][oc]
    const int z0 = 2 * pz + dz;
    const int y0 = 2 * py;                    // dy=0 row; dy=1 via +192 els
    const float sl = slope[0];

    int ab[3];
    #pragma unroll
    for (int xt = 0; xt < 3; ++xt) {
        int x = xt * 16 + l15;
        int xr = x > 41 ? 41 : x;
        ab[xt] = (((n * 47 + z0) * 47 + y0) * 48 + xr) * 4;
    }

    f32x4 acc[2][3][2] = {};                  // [dy][xt][ot]
    const f16x8* Bv = (const f16x8*)Bp;

    f16x8 avd[3][3][2], b0v[3], b1v[3];       // [j][xt][dy]
    int dlv[3];
    dlv[0] = Dtx[lane]; dlv[1] = Dtx[64 + lane]; dlv[2] = Dtx[128 + lane];

    auto LOADS = [&](int s, int j) {
        int delta = dlv[j];
        dlv[j] = Dtx[(s + 3 > 18 ? 18 : s + 3) * 64 + lane];   // distance-3 prefetch
        b0v[j] = Bv[(2 * s) * 64 + lane];
        b1v[j] = Bv[(2 * s + 1) * 64 + lane];
        #pragma unroll
        for (int xt = 0; xt < 3; ++xt) {
            int vo = ab[xt] + delta;
            avd[j][xt][0] = *(const f16x8u*)(hi0 + vo);
            avd[j][xt][1] = *(const f16x8u*)(hi0 + vo + 192);  // dy=1: +1 y-row
        }
    };
    auto COMP = [&](int j) {
        #pragma unroll
        for (int xt = 0; xt < 3; ++xt)
            #pragma unroll
            for (int dy = 0; dy < 2; ++dy) {
                acc[dy][xt][0] = MFMA16(avd[j][xt][dy], b0v[j], acc[dy][xt][0]);
                acc[dy][xt][1] = MFMA16(avd[j][xt][dy], b1v[j], acc[dy][xt][1]);
            }
    };

    LOADS(0, 0); SB(); LOADS(1, 1); SB();
    for (int s = 0; s < 18; s += 3) {
        LOADS(s + 2, 2); SB(); COMP(0); SB();
        LOADS(s + 3, 0); SB(); COMP(1); SB();
        if (s + 4 < 19) LOADS(s + 4, 1);
        SB(); COMP(2); SB();
    }
    COMP(0);                                   // step 18

    #pragma unroll
    for (int xt = 0; xt < 3; ++xt)
        #pragma unroll
        for (int ot = 0; ot < 2; ++ot) {
            float m0 = fmaxf(acc[0][xt][ot][0], acc[1][xt][ot][0]);
            float m1 = fmaxf(acc[0][xt][ot][1], acc[1][xt][ot][1]);
            float m2 = fmaxf(acc[0][xt][ot][2], acc[1][xt][ot][2]);
            float m3 = fmaxf(acc[0][xt][ot][3], acc[1][xt][ot][3]);
            int pxe = xt * 8 + 2 * q, pxo = pxe + 1;
            if (pxe < 21) pool[dz][pyl][pxe][ot * 16 + l15] = fmaxf(m0, m1);
            if (pxo < 21) pool[dz][pyl][pxo][ot * 16 + l15] = fmaxf(m2, m3);
        }
    __syncthreads();

    for (int t2 = tid; t2 < 1344; t2 += 256) {
        int oc = t2 & 31, r = t2 >> 5;
        int px = r % 21, pyl2 = r / 21;
        int py2 = 2 * pyg + pyl2;
        if (py2 > 20) continue;
        float v = fmaxf(pool[0][pyl2][px][oc], pool[1][pyl2][px][oc]);
        v += bias[oc];
        v = (v >= 0.f) ? v : sl * v;
        int o = (((n * 23 + pz + 1) * 23 + py2 + 1) * 24 + px + 1) * 32 + oc;
        hi1[o] = f2h(v);
    }
}

// ---- conv1 MFMA: hi1 [80][23][23][24][32] f16 -> P2 fp32 NCDHW padded
// block = (n, pz, py-group of 3); wave = (dz,dy); M flattened over (py_local,x):
// flat = pyl*18 + x in [0,54), 4 m-tiles of 16 (15.6% waste).
// R10: sched_barrier-pinned pipeline + rotating scalar-offset prefetch.
__global__ __launch_bounds__(256, 3)
void conv1_mfma(const ushort* __restrict__ hi1,
                const ushort* __restrict__ Bp, const int* __restrict__ Dt,
                const float* __restrict__ bias, const float* __restrict__ slope,
                float* __restrict__ P2)
{
    const int n   = blockIdx.z;
    const int pz  = blockIdx.x / 3, pyg = blockIdx.x % 3;
    const int tid = threadIdx.x, lane = tid & 63, w = tid >> 6;
    const int dz = w >> 1, dy = w & 1;
    const int q = lane >> 4, l15 = lane & 15;

    __shared__ float pool[4][27][32];
    const int z0 = 2 * pz + dz;

    int ab[4];
    #pragma unroll
    for (int t = 0; t < 4; ++t) {
        int flat = t * 16 + l15;
        if (flat > 53) flat = 53;
        int pyl = flat / 18, x = flat - pyl * 18;
        int y0 = 2 * (pyg * 3 + pyl) + dy;
        ab[t] = ((((n * 23 + z0) * 23 + y0) * 24 + x) << 5) + q * 8;
    }

    f32x4 acc[4][2] = {};
    const f16x8* Bv = (const f16x8*)Bp;

    constexpr int STEPS = 126;               // divisible by 3
    f16x8 ahv[3][4], b0v[3], b1v[3];
    int offv[3];
    offv[0] = Dt[0]; offv[1] = Dt[1]; offv[2] = Dt[2];

    auto LOADS = [&](int s, int j) {
        int off = offv[j];
        offv[j] = Dt[s + 3 > 125 ? 125 : s + 3];               // scalar prefetch
        b0v[j] = Bv[(2 * s) * 64 + lane];
        b1v[j] = Bv[(2 * s + 1) * 64 + lane];
        #pragma unroll
        for (int t = 0; t < 4; ++t)
            ahv[j][t] = *(const f16x8*)(hi1 + ab[t] + off);    // 16B aligned
    };
    auto COMP = [&](int j) {
        #pragma unroll
        for (int t = 0; t < 4; ++t) {
            acc[t][0] = MFMA16(ahv[j][t], b0v[j], acc[t][0]);
            acc[t][1] = MFMA16(ahv[j][t], b1v[j], acc[t][1]);
        }
    };

    LOADS(0, 0); SB(); LOADS(1, 1); SB();
    for (int s = 0; s < STEPS; s += 3) {
        LOADS(s + 2, 2); SB(); COMP(0); SB();
        if (s + 3 < STEPS) LOADS(s + 3, 0);
        SB(); COMP(1); SB();
        if (s + 4 < STEPS) LOADS(s + 4, 1);
        SB(); COMP(2); SB();
    }

    // D rows m=q*4+reg of tile t -> flat = t*16+q*4+reg; x-pairs = (reg0,reg1),(reg2,reg3)
    #pragma unroll
    for (int t = 0; t < 4; ++t) {
        int p0 = t * 8 + q * 2;
        float e0 = fmaxf(acc[t][0][0], acc[t][0][1]);
        float o0 = fmaxf(acc[t][0][2], acc[t][0][3]);
        float e1 = fmaxf(acc[t][1][0], acc[t][1][1]);
        float o1 = fmaxf(acc[t][1][2], acc[t][1][3]);
        if (p0 < 27)     { pool[w][p0][l15] = e0;     pool[w][p0][16 + l15] = e1; }
        if (p0 + 1 < 27) { pool[w][p0 + 1][l15] = o0; pool[w][p0 + 1][16 + l15] = o1; }
    }
    __syncthreads();

    for (int t2 = tid; t2 < 864; t2 += 256) {
        int oc = t2 & 31, pr = t2 >> 5;          // pr = pyl*9 + px
        int pyl = pr / 9, px = pr % 9;
        float v = fmaxf(fmaxf(pool[0][pr][oc], pool[1][pr][oc]),
                        fmaxf(pool[2][pr][oc], pool[3][pr][oc]));
        v += bias[oc];
        float s0 = slope[0];
        v = (v >= 0.f) ? v : s0 * v;
        int py = pyg * 3 + pyl;
        P2[(long)n * 32 * 11 * 11 * 12 +
           ((oc * 11 + pz + 1) * 11 + py + 1) * 12 + px + 1] = v;
    }
}

// ---- conv2 (fp32 direct, R4-verified) ----
template<int CIN, int K, int SY, int SXS, int ICS, int SPOOL, int PX,
         int OXS, int OPAD>
__global__ __launch_bounds__(256, 2)
void conv_pool_kernel(const float* __restrict__ in,
                      const float* __restrict__ w,
                      const float* __restrict__ bias,
                      const float* __restrict__ slope,
                      float* __restrict__ out,
                      float scale)
{
    constexpr int NX  = 2 * PX;
    constexpr int LX  = NX + K - 1;
    constexpr int LX2 = (LX + 1) / 2;
    constexpr int XT  = SPOOL / PX;
    constexpr int OD  = SPOOL + 2 * OPAD;

    const int oc   = blockIdx.y;
    const int n    = blockIdx.z;
    const int COUT = gridDim.y;

    int idx = blockIdx.x * blockDim.x + threadIdx.x;
    const int POS = XT * SPOOL * SPOOL;
    if (idx >= POS) return;

    int xt  = idx % XT;
    int py  = (idx / XT) % SPOOL;
    int pz  = idx / (XT * SPOOL);
    int px0 = xt * PX;

    const float* inb = in + (long)n * CIN * ICS + (2 * pz * SY + 2 * py) * SXS + 2 * px0;
    const float* wb  = w + (long)oc * CIN * K * K * K;

    float acc[2][2][NX] = {};

    #pragma unroll 1
    for (int ic = 0; ic < CIN; ++ic) {
        const float* inc = inb + (long)ic * ICS;
        const float* wic = wb + ic * K * K * K;
        #pragma unroll
        for (int tz = 0; tz < K + 1; ++tz) {
            #pragma unroll
            for (int ty = 0; ty < K + 1; ++ty) {
                const float2* rp = (const float2*)(inc + (tz * SY + ty) * SXS);
                float row[LX2 * 2];
                #pragma unroll
                for (int i = 0; i < LX2; ++i) {
                    float2 t = rp[i];
                    row[2 * i] = t.x; row[2 * i + 1] = t.y;
                }
                #pragma unroll
                for (int dzz = 0; dzz < 2; ++dzz) {
                    if (tz - dzz < 0 || tz - dzz >= K) continue;
                    #pragma unroll
                    for (int dyy = 0; dyy < 2; ++dyy) {
                        if (ty - dyy < 0 || ty - dyy >= K) continue;
                        const float* wrow = wic + ((tz - dzz) * K + (ty - dyy)) * K;
                        #pragma unroll
                        for (int kx = 0; kx < K; ++kx) {
                            float wv = wrow[kx];
                            #pragma unroll
                            for (int dx = 0; dx < NX; ++dx)
                                acc[dzz][dyy][dx] += wv * row[kx + dx];
                        }
                    }
                }
            }
        }
    }

    float b = bias[oc];
    float a = slope[0];
    long ob = ((long)n * COUT + oc) * (OD * OD * OXS)
            + (long)(pz + OPAD) * (OD * OXS) + (py + OPAD) * OXS + OPAD + px0;
    #pragma unroll
    for (int j = 0; j < PX; ++j) {
        float m = -3.4e38f;
        #pragma unroll
        for (int dzz = 0; dzz < 2; ++dzz)
            #pragma unroll
            for (int dyy = 0; dyy < 2; ++dyy)
                #pragma unroll
                for (int dx = 0; dx < 2; ++dx) {
                    float v = acc[dzz][dyy][2 * j + dx] * scale + b;
                    v = (v >= 0.f) ? v : a * v;
                    m = fmaxf(m, v);
                }
        out[ob + j] = m;
    }
}

// ---- conv3 (fp32 direct) ----
__global__ void conv3_kernel(const float* __restrict__ in,
                             const float* __restrict__ w,
                             const float* __restrict__ bias,
                             const float* __restrict__ slope,
                             float* __restrict__ out)
{
    int idx = blockIdx.x * blockDim.x + threadIdx.x;
    const int TOTAL = 80 * 64 * 8;
    if (idx >= TOTAL) return;
    int p  = idx & 7;
    int oc = (idx >> 3) & 63;
    int n  = idx >> 9;
    int ox = p & 1, oy = (p >> 1) & 1, oz = p >> 2;

    const float* inb = in + (long)n * 64 * 64;
    const float* wb  = w + (long)oc * 64 * 27;

    float acc = 0.f;
    for (int ic = 0; ic < 64; ++ic) {
        const float* inc = inb + ic * 64;
        const float* wc  = wb + ic * 27;
        #pragma unroll
        for (int kz = 0; kz < 3; ++kz)
            #pragma unroll
            for (int ky = 0; ky < 3; ++ky)
                #pragma unroll
                for (int kx = 0; kx < 3; ++kx)
                    acc += wc[(kz * 3 + ky) * 3 + kx] *
                           inc[((oz + kz) * 4 + (oy + ky)) * 4 + (ox + kx)];
    }
    float v = acc + bias[oc];
    float a = slope[0];
    v = (v >= 0.f) ? v : a * v;
    out[idx] = v;
}

// ---- comm-FC ----
template<int D, int O, bool PRELU_ON>
__global__ void comm_fc_kernel(const float* __restrict__ feat,
                               const float* __restrict__ w,
                               const float* __restrict__ bias,
                               const float* __restrict__ slope,
                               float* __restrict__ out)
{
    const int a = blockIdx.x;
    const int b = blockIdx.y;

    __shared__ __align__(16) float cat[2 * D];
    for (int i = threadIdx.x; i < D; i += blockDim.x) {
        float m = 0.f;
        #pragma unroll
        for (int aa = 0; aa < 5; ++aa) m += feat[(b * 5 + aa) * D + i];
        cat[i]     = feat[(b * 5 + a) * D + i];
        cat[D + i] = m * 0.2f;
    }
    __syncthreads();

    for (int o = threadIdx.x; o < O; o += blockDim.x) {
        const float4* wr = (const float4*)(w + ((long)(a * O) + o) * 2 * D);
        const float4* cr = (const float4*)cat;
        float acc = 0.f;
        for (int i = 0; i < 2 * D / 4; ++i) {
            float4 wv = wr[i];
            float4 cv = cr[i];
            acc += wv.x * cv.x + wv.y * cv.y + wv.z * cv.z + wv.w * cv.w;
        }
        acc += bias[a * O + o];
        if constexpr (PRELU_ON) {
            float s = slope[0];
            acc = (acc >= 0.f) ? acc : s * acc;
        }
        out[(b * 5 + a) * O + o] = acc;
    }
}

extern "C" void kernel_launch(void* const* d_in, const int* in_sizes, int n_in,
                              void* d_out, int out_size, void* d_ws, size_t ws_size,
                              hipStream_t stream)
{
    const float* x    = (const float*)d_in[0];
    const float* c0w  = (const float*)d_in[1];
    const float* c0b  = (const float*)d_in[2];
    const float* p0   = (const float*)d_in[3];
    const float* c1w  = (const float*)d_in[4];
    const float* c1b  = (const float*)d_in[5];
    const float* p1   = (const float*)d_in[6];
    const float* c2w  = (const float*)d_in[7];
    const float* c2b  = (const float*)d_in[8];
    const float* p2   = (const float*)d_in[9];
    const float* c3w  = (const float*)d_in[10];
    const float* c3b  = (const float*)d_in[11];
    const float* p3   = (const float*)d_in[12];
    const float* f1w  = (const float*)d_in[13];
    const float* f1b  = (const float*)d_in[14];
    const float* p4   = (const float*)d_in[15];
    const float* f2w  = (const float*)d_in[16];
    const float* f2b  = (const float*)d_in[17];
    const float* p5   = (const float*)d_in[18];
    const float* f3w  = (const float*)d_in[19];
    const float* f3b  = (const float*)d_in[20];

    char* ws = (char*)d_ws;
    ushort* hi0  = (ushort*)(ws);                         // 33,930,240 el f16
    ushort* hi1  = (ushort*)(ws + 67860480);              // 32,501,760 el f16
    float*  P2   = (float*) (ws + 132864000);             //  3,717,120 el
    float*  P3   = (float*) (ws + 147732480);             //    327,680 el
    float*  feat0= (float*) (ws + 149043200);
    float*  feat1= (float*) (ws + 149207040);
    float*  feat2= (float*) (ws + 149288960);
    ushort* Bp0  = (ushort*)(ws + 149329920);             // 19,456 el
    ushort* Bp1  = (ushort*)(ws + 149368832);             // 129,024 el
    int*    Dtx0 = (int*)   (ws + 149626880);             // 19*64 = 1216 el
    int*    Dt1  = (int*)   (ws + 149631744);             // 126 el

    // zero halos of hi0/hi1 + all of P2
    hipMemsetAsync(ws, 0, 147732480, stream);

    pack_w0<<<76, 256, 0, stream>>>(c0w, Bp0, Dtx0);
    pack_w1<<<504, 256, 0, stream>>>(c1w, Bp1, Dt1);
    pad_input_kernel<<<(7290000 + 255) / 256, 256, 0, stream>>>(x, hi0);

    conv0_mfma<<<dim3(231, 1, 80), 256, 0, stream>>>(hi0, Bp0, Dtx0,
                                                     c0b, p0, hi1);
    conv1_mfma<<<dim3(27, 1, 80), 256, 0, stream>>>(hi1, Bp1, Dt1,
                                                    c1b, p1, P2);

    conv_pool_kernel<32, 4, 11, 12, 1452, 4, 1, 4, 0>
        <<<dim3(1, 64, 80), dim3(64), 0, stream>>>(P2, c2w, c2b, p2, P3, 1.f);

    conv3_kernel<<<dim3(160), dim3(256), 0, stream>>>(P3, c3w, c3b, p3, feat0);

    comm_fc_kernel<512, 256, true>
        <<<dim3(5, 16), dim3(256), 0, stream>>>(feat0, f1w, f1b, p4, feat1);
    comm_fc_kernel<256, 128, true>
        <<<dim3(5, 16), dim3(256), 0, stream>>>(feat1, f2w, f2b, p5, feat2);
    comm_fc_kernel<128, 6, false>
        <<<dim3(5, 16), dim3(64), 0, stream>>>(feat2, f3w, f3b, nullptr, (float*)d_out);
}

// Round 3
// 1315.585 us; speedup vs baseline: 1.2693x; 1.2693x over previous
//
#include <hip/hip_runtime.h>

// ---------------------------------------------------------------------------
// CommNet round 11: dy-merge WITHOUT spills; B in LDS.
//  R10 post-mortem: WRITE_SIZE 46->646 MB = scratch spills (sched_barrier
//  pinning + PF=3 + per-lane delta regs + launch_bounds cap). MfmaUtil 16.
//  Model: conv0 is L1/VMEM-byte bound (~8KB VMEM per wave-step). Keep R10's
//  dy-merge (12 MFMA per 6 A-loads: halves L1 bytes/MFMA vs R9), but:
//   - PF=2 rotation, no sched_barriers, launch_bounds(256,2) -> no spill
//   - B (38.9 KB, all 19 steps) staged once in LDS -> 2KB/step off the L1 pipe
//   - branch-free main loop (tail peeled) so the scheduler can pipeline
//   - delta select back to int4 + cndmask (no extra VMEM in L1-bound regime)
//  conv1: R9 structure + peeled branch-free tail only.
// Layouts (HW-verified): A[m=lane&15][k=q*8+j], B[n=lane&15][k=q*8+j],
//  D col=lane&15, row=q*4+reg.
// ---------------------------------------------------------------------------

typedef __attribute__((ext_vector_type(8)))  _Float16 f16x8;
typedef __attribute__((ext_vector_type(8), aligned(8))) _Float16 f16x8u; // 8B-aligned 16B load
typedef __attribute__((ext_vector_type(4)))  float f32x4;

__device__ __forceinline__ ushort f2h(float f) {
    union { _Float16 h; ushort u; } v;
    v.h = (_Float16)f;                       // v_cvt_f16_f32, RNE
    return v.u;
}

#define MFMA16(A, B, C) __builtin_amdgcn_mfma_f32_16x16x32_f16(A, B, C, 0, 0, 0)

// ---- prep: x [80][4][45^3] fp32 -> hi0 NDHWC padded [80][47][47][48][4] f16
__global__ void pad_input_kernel(const float* __restrict__ x,
                                 ushort* __restrict__ hi)
{
    int t = blockIdx.x * 256 + threadIdx.x;
    const int TOT = 80 * 45 * 45 * 45;
    if (t >= TOT) return;
    int xi = t % 45, r = t / 45;
    int y = r % 45; r /= 45;
    int z = r % 45; int n = r / 45;
    int ib = ((n * 4) * 91125) + z * 2025 + y * 45 + xi;
    int ob = (((n * 47 + z + 1) * 47 + y + 1) * 48 + xi + 1) * 4;
    ushort h4[4];
    #pragma unroll
    for (int ic = 0; ic < 4; ++ic) {
        float v = x[ib + ic * 91125] * (1.f / 255.f);
        h4[ic] = f2h(v);
    }
    *(ushort4*)(hi + ob) = *(ushort4*)h4;
}

// ---- pack conv0 weights [32][4][5][5][5] -> Bp0[19 s][2 ot][64 lane][8 j] f16
// k = ((kz*5+ky)*6+kx)*4 + ic  (kx in [0,6), kx==5 zero; K=600, 19 steps = 608)
__global__ void pack_w0(const float* __restrict__ w, ushort* __restrict__ Bp,
                        int4* __restrict__ Dt)
{
    int t = blockIdx.x * 256 + threadIdx.x;
    if (t < 19 * 2 * 64 * 8) {
        int j = t & 7, l = (t >> 3) & 63, ot = (t >> 9) & 1, s = t >> 10;
        int oc = ot * 16 + (l & 15);
        int k = 32 * s + ((l >> 4) << 3) + j;
        float v = 0.f;
        if (k < 600) {
            int ic = k & 3, t6 = k >> 2;
            int kx = t6 % 6, q = t6 / 6, ky = q % 5, kz = q / 5;
            if (kx < 5) v = w[(oc * 4 + ic) * 125 + kz * 25 + ky * 5 + kx];
        }
        Bp[t] = f2h(v);
    }
    if (t < 19) {
        int dd[4];
        #pragma unroll
        for (int q = 0; q < 4; ++q) {
            int k = 32 * t + 8 * q;
            if (k < 600) {
                int t6 = k >> 2;
                int kx = t6 % 6, qq = t6 / 6;
                dd[q] = (((qq / 5) * 47 + (qq % 5)) * 48 + kx) * 4;  // x-unit=4
            } else dd[q] = 0;
        }
        int4 d; d.x = dd[0]; d.y = dd[1]; d.z = dd[2]; d.w = dd[3];
        Dt[t] = d;
    }
}

// ---- pack conv1 weights [32][32][5][5][5] -> Bp1[126 s][2 ot][64][8] f16
// step s = tap (125 real, 1 zero pad), k = s*32 + ic
__global__ void pack_w1(const float* __restrict__ w, ushort* __restrict__ Bp,
                        int* __restrict__ Dt)
{
    int t = blockIdx.x * 256 + threadIdx.x;
    if (t < 126 * 2 * 64 * 8) {
        int j = t & 7, l = (t >> 3) & 63, ot = (t >> 9) & 1, s = t >> 10;
        int oc = ot * 16 + (l & 15);
        int ic = ((l >> 4) << 3) + j;
        Bp[t] = (s < 125) ? f2h(w[(oc * 32 + ic) * 125 + s]) : (ushort)0;
    }
    if (t < 126) {
        if (t < 125) {
            int kz = t / 25, ky = (t / 5) % 5, kx = t % 5;
            Dt[t] = ((kz * 23 + ky) * 24 + kx) * 32;                 // x-unit=32
        } else Dt[t] = 0;
    }
}

// ---- conv0 MFMA: hi0 [80][47][47][48][4] f16 -> hi1 [80][23][23][24][32] f16
// block = (pz, pyg) covering py = 2*pyg + {0,1}; wave w: dz=w>>1, pyl=w&1.
// Each wave computes BOTH dy rows (A offset +192 els), dy-max in-register.
// B for all 19 steps resident in LDS (staged once).
__global__ __launch_bounds__(256, 2)
void conv0_mfma(const ushort* __restrict__ hi0,
                const ushort* __restrict__ Bp, const int4* __restrict__ Dt,
                const float* __restrict__ bias, const float* __restrict__ slope,
                ushort* __restrict__ hi1)
{
    const int n   = blockIdx.z;
    const int pz  = blockIdx.x / 11, pyg = blockIdx.x % 11;
    const int tid = threadIdx.x, lane = tid & 63, w = tid >> 6;
    const int dz  = w >> 1, pyl = w & 1;
    const int py  = 2 * pyg + pyl;            // may be 21 (invalid, pyg==10)
    const int l15 = lane & 15, q = lane >> 4;

    __shared__ float pool[2][2][21][32];      // [dz][pyl][px][oc]
    __shared__ __align__(16) ushort Bl[19 * 2 * 64 * 8];   // 38912 B

    {   // stage all B into LDS once (2432 x 16B)
        const uint4* src = (const uint4*)Bp;
        uint4* dst = (uint4*)Bl;
        for (int i = tid; i < 2432; i += 256) dst[i] = src[i];
    }

    const int z0 = 2 * pz + dz;
    const int y0 = 2 * py;                    // dy=0 row; dy=1 via +192 els
    const float sl = slope[0];

    int ab[3];
    #pragma unroll
    for (int xt = 0; xt < 3; ++xt) {
        int x = xt * 16 + l15;
        int xr = x > 41 ? 41 : x;
        ab[xt] = (((n * 47 + z0) * 47 + y0) * 48 + xr) * 4;
    }

    f32x4 acc[2][3][2] = {};                  // [dy][xt][ot]
    const f16x8* BL = (const f16x8*)Bl;

    f16x8 avd[2][3][2];                       // [j][xt][dy]

    auto LOADS = [&](int s, int j) {
        int4 dd = Dt[s];
        int delta = q == 0 ? dd.x : q == 1 ? dd.y : q == 2 ? dd.z : dd.w;
        #pragma unroll
        for (int xt = 0; xt < 3; ++xt) {
            int vo = ab[xt] + delta;
            avd[j][xt][0] = *(const f16x8u*)(hi0 + vo);
            avd[j][xt][1] = *(const f16x8u*)(hi0 + vo + 192);  // dy=1: +1 y-row
        }
    };
    auto COMP = [&](int s, int j) {
        f16x8 b0 = BL[(2 * s) * 64 + lane];
        f16x8 b1 = BL[(2 * s + 1) * 64 + lane];
        #pragma unroll
        for (int xt = 0; xt < 3; ++xt)
            #pragma unroll
            for (int dy = 0; dy < 2; ++dy) {
                acc[dy][xt][0] = MFMA16(avd[j][xt][dy], b0, acc[dy][xt][0]);
                acc[dy][xt][1] = MFMA16(avd[j][xt][dy], b1, acc[dy][xt][1]);
            }
    };

    __syncthreads();                          // B staged

    LOADS(0, 0); LOADS(1, 1);
    for (int s = 0; s < 16; s += 2) {         // branch-free body
        COMP(s, 0);     LOADS(s + 2, 0);
        COMP(s + 1, 1); LOADS(s + 3, 1);      // max s+3 = 17
    }
    COMP(16, 0); LOADS(18, 0);
    COMP(17, 1);
    COMP(18, 0);

    #pragma unroll
    for (int xt = 0; xt < 3; ++xt)
        #pragma unroll
        for (int ot = 0; ot < 2; ++ot) {
            float m0 = fmaxf(acc[0][xt][ot][0], acc[1][xt][ot][0]);
            float m1 = fmaxf(acc[0][xt][ot][1], acc[1][xt][ot][1]);
            float m2 = fmaxf(acc[0][xt][ot][2], acc[1][xt][ot][2]);
            float m3 = fmaxf(acc[0][xt][ot][3], acc[1][xt][ot][3]);
            int pxe = xt * 8 + 2 * q, pxo = pxe + 1;
            if (pxe < 21) pool[dz][pyl][pxe][ot * 16 + l15] = fmaxf(m0, m1);
            if (pxo < 21) pool[dz][pyl][pxo][ot * 16 + l15] = fmaxf(m2, m3);
        }
    __syncthreads();

    for (int t2 = tid; t2 < 1344; t2 += 256) {
        int oc = t2 & 31, r = t2 >> 5;
        int px = r % 21, pyl2 = r / 21;
        int py2 = 2 * pyg + pyl2;
        if (py2 > 20) continue;
        float v = fmaxf(pool[0][pyl2][px][oc], pool[1][pyl2][px][oc]);
        v += bias[oc];
        v = (v >= 0.f) ? v : sl * v;
        int o = (((n * 23 + pz + 1) * 23 + py2 + 1) * 24 + px + 1) * 32 + oc;
        hi1[o] = f2h(v);
    }
}

// ---- conv1 MFMA: hi1 [80][23][23][24][32] f16 -> P2 fp32 NCDHW padded
// block = (n, pz, py-group of 3); wave = (dz,dy); M flattened over (py_local,x):
// flat = pyl*18 + x in [0,54), 4 m-tiles of 16 (15.6% waste).
// R11: R9 structure, branch-free body (tail peeled).
__global__ __launch_bounds__(256)
void conv1_mfma(const ushort* __restrict__ hi1,
                const ushort* __restrict__ Bp, const int* __restrict__ Dt,
                const float* __restrict__ bias, const float* __restrict__ slope,
                float* __restrict__ P2)
{
    const int n   = blockIdx.z;
    const int pz  = blockIdx.x / 3, pyg = blockIdx.x % 3;
    const int tid = threadIdx.x, lane = tid & 63, w = tid >> 6;
    const int dz = w >> 1, dy = w & 1;
    const int q = lane >> 4, l15 = lane & 15;

    __shared__ float pool[4][27][32];
    const int z0 = 2 * pz + dz;

    int ab[4];
    #pragma unroll
    for (int t = 0; t < 4; ++t) {
        int flat = t * 16 + l15;
        if (flat > 53) flat = 53;
        int pyl = flat / 18, x = flat - pyl * 18;
        int y0 = 2 * (pyg * 3 + pyl) + dy;
        ab[t] = ((((n * 23 + z0) * 23 + y0) * 24 + x) << 5) + q * 8;
    }

    f32x4 acc[4][2] = {};
    const f16x8* Bv = (const f16x8*)Bp;

    f16x8 ahv[3][4], b0v[3], b1v[3];

    auto LOADS = [&](int s, int j) {
        int off = Dt[s];
        b0v[j] = Bv[(2 * s) * 64 + lane];
        b1v[j] = Bv[(2 * s + 1) * 64 + lane];
        #pragma unroll
        for (int t = 0; t < 4; ++t)
            ahv[j][t] = *(const f16x8*)(hi1 + ab[t] + off);    // 16B aligned
    };
    auto COMP = [&](int j) {
        #pragma unroll
        for (int t = 0; t < 4; ++t) {
            acc[t][0] = MFMA16(ahv[j][t], b0v[j], acc[t][0]);
            acc[t][1] = MFMA16(ahv[j][t], b1v[j], acc[t][1]);
        }
    };

    LOADS(0, 0); LOADS(1, 1);
    for (int s = 0; s < 123; s += 3) {        // branch-free: loads to s+4<=124
        LOADS(s + 2, 2); COMP(0);
        LOADS(s + 3, 0); COMP(1);
        LOADS(s + 4, 1); COMP(2);
    }
    LOADS(125, 2);                            // buf0=123, buf1=124 already loaded
    COMP(0); COMP(1); COMP(2);

    // D rows m=q*4+reg of tile t -> flat = t*16+q*4+reg; x-pairs = (reg0,reg1),(reg2,reg3)
    #pragma unroll
    for (int t = 0; t < 4; ++t) {
        int p0 = t * 8 + q * 2;
        float e0 = fmaxf(acc[t][0][0], acc[t][0][1]);
        float o0 = fmaxf(acc[t][0][2], acc[t][0][3]);
        float e1 = fmaxf(acc[t][1][0], acc[t][1][1]);
        float o1 = fmaxf(acc[t][1][2], acc[t][1][3]);
        if (p0 < 27)     { pool[w][p0][l15] = e0;     pool[w][p0][16 + l15] = e1; }
        if (p0 + 1 < 27) { pool[w][p0 + 1][l15] = o0; pool[w][p0 + 1][16 + l15] = o1; }
    }
    __syncthreads();

    for (int t2 = tid; t2 < 864; t2 += 256) {
        int oc = t2 & 31, pr = t2 >> 5;          // pr = pyl*9 + px
        int pyl = pr / 9, px = pr % 9;
        float v = fmaxf(fmaxf(pool[0][pr][oc], pool[1][pr][oc]),
                        fmaxf(pool[2][pr][oc], pool[3][pr][oc]));
        v += bias[oc];
        float s0 = slope[0];
        v = (v >= 0.f) ? v : s0 * v;
        int py = pyg * 3 + pyl;
        P2[(long)n * 32 * 11 * 11 * 12 +
           ((oc * 11 + pz + 1) * 11 + py + 1) * 12 + px + 1] = v;
    }
}

// ---- conv2 (fp32 direct, R4-verified) ----
template<int CIN, int K, int SY, int SXS, int ICS, int SPOOL, int PX,
         int OXS, int OPAD>
__global__ __launch_bounds__(256, 2)
void conv_pool_kernel(const float* __restrict__ in,
                      const float* __restrict__ w,
                      const float* __restrict__ bias,
                      const float* __restrict__ slope,
                      float* __restrict__ out,
                      float scale)
{
    constexpr int NX  = 2 * PX;
    constexpr int LX  = NX + K - 1;
    constexpr int LX2 = (LX + 1) / 2;
    constexpr int XT  = SPOOL / PX;
    constexpr int OD  = SPOOL + 2 * OPAD;

    const int oc   = blockIdx.y;
    const int n    = blockIdx.z;
    const int COUT = gridDim.y;

    int idx = blockIdx.x * blockDim.x + threadIdx.x;
    const int POS = XT * SPOOL * SPOOL;
    if (idx >= POS) return;

    int xt  = idx % XT;
    int py  = (idx / XT) % SPOOL;
    int pz  = idx / (XT * SPOOL);
    int px0 = xt * PX;

    const float* inb = in + (long)n * CIN * ICS + (2 * pz * SY + 2 * py) * SXS + 2 * px0;
    const float* wb  = w + (long)oc * CIN * K * K * K;

    float acc[2][2][NX] = {};

    #pragma unroll 1
    for (int ic = 0; ic < CIN; ++ic) {
        const float* inc = inb + (long)ic * ICS;
        const float* wic = wb + ic * K * K * K;
        #pragma unroll
        for (int tz = 0; tz < K + 1; ++tz) {
            #pragma unroll
            for (int ty = 0; ty < K + 1; ++ty) {
                const float2* rp = (const float2*)(inc + (tz * SY + ty) * SXS);
                float row[LX2 * 2];
                #pragma unroll
                for (int i = 0; i < LX2; ++i) {
                    float2 t = rp[i];
                    row[2 * i] = t.x; row[2 * i + 1] = t.y;
                }
                #pragma unroll
                for (int dzz = 0; dzz < 2; ++dzz) {
                    if (tz - dzz < 0 || tz - dzz >= K) continue;
                    #pragma unroll
                    for (int dyy = 0; dyy < 2; ++dyy) {
                        if (ty - dyy < 0 || ty - dyy >= K) continue;
                        const float* wrow = wic + ((tz - dzz) * K + (ty - dyy)) * K;
                        #pragma unroll
                        for (int kx = 0; kx < K; ++kx) {
                            float wv = wrow[kx];
                            #pragma unroll
                            for (int dx = 0; dx < NX; ++dx)
                                acc[dzz][dyy][dx] += wv * row[kx + dx];
                        }
                    }
                }
            }
        }
    }

    float b = bias[oc];
    float a = slope[0];
    long ob = ((long)n * COUT + oc) * (OD * OD * OXS)
            + (long)(pz + OPAD) * (OD * OXS) + (py + OPAD) * OXS + OPAD + px0;
    #pragma unroll
    for (int j = 0; j < PX; ++j) {
        float m = -3.4e38f;
        #pragma unroll
        for (int dzz = 0; dzz < 2; ++dzz)
            #pragma unroll
            for (int dyy = 0; dyy < 2; ++dyy)
                #pragma unroll
                for (int dx = 0; dx < 2; ++dx) {
                    float v = acc[dzz][dyy][2 * j + dx] * scale + b;
                    v = (v >= 0.f) ? v : a * v;
                    m = fmaxf(m, v);
                }
        out[ob + j] = m;
    }
}

// ---- conv3 (fp32 direct) ----
__global__ void conv3_kernel(const float* __restrict__ in,
                             const float* __restrict__ w,
                             const float* __restrict__ bias,
                             const float* __restrict__ slope,
                             float* __restrict__ out)
{
    int idx = blockIdx.x * blockDim.x + threadIdx.x;
    const int TOTAL = 80 * 64 * 8;
    if (idx >= TOTAL) return;
    int p  = idx & 7;
    int oc = (idx >> 3) & 63;
    int n  = idx >> 9;
    int ox = p & 1, oy = (p >> 1) & 1, oz = p >> 2;

    const float* inb = in + (long)n * 64 * 64;
    const float* wb  = w + (long)oc * 64 * 27;

    float acc = 0.f;
    for (int ic = 0; ic < 64; ++ic) {
        const float* inc = inb + ic * 64;
        const float* wc  = wb + ic * 27;
        #pragma unroll
        for (int kz = 0; kz < 3; ++kz)
            #pragma unroll
            for (int ky = 0; ky < 3; ++ky)
                #pragma unroll
                for (int kx = 0; kx < 3; ++kx)
                    acc += wc[(kz * 3 + ky) * 3 + kx] *
                           inc[((oz + kz) * 4 + (oy + ky)) * 4 + (ox + kx)];
    }
    float v = acc + bias[oc];
    float a = slope[0];
    v = (v >= 0.f) ? v : a * v;
    out[idx] = v;
}

// ---- comm-FC ----
template<int D, int O, bool PRELU_ON>
__global__ void comm_fc_kernel(const float* __restrict__ feat,
                               const float* __restrict__ w,
                               const float* __restrict__ bias,
                               const float* __restrict__ slope,
                               float* __restrict__ out)
{
    const int a = blockIdx.x;
    const int b = blockIdx.y;

    __shared__ __align__(16) float cat[2 * D];
    for (int i = threadIdx.x; i < D; i += blockDim.x) {
        float m = 0.f;
        #pragma unroll
        for (int aa = 0; aa < 5; ++aa) m += feat[(b * 5 + aa) * D + i];
        cat[i]     = feat[(b * 5 + a) * D + i];
        cat[D + i] = m * 0.2f;
    }
    __syncthreads();

    for (int o = threadIdx.x; o < O; o += blockDim.x) {
        const float4* wr = (const float4*)(w + ((long)(a * O) + o) * 2 * D);
        const float4* cr = (const float4*)cat;
        float acc = 0.f;
        for (int i = 0; i < 2 * D / 4; ++i) {
            float4 wv = wr[i];
            float4 cv = cr[i];
            acc += wv.x * cv.x + wv.y * cv.y + wv.z * cv.z + wv.w * cv.w;
        }
        acc += bias[a * O + o];
        if constexpr (PRELU_ON) {
            float s = slope[0];
            acc = (acc >= 0.f) ? acc : s * acc;
        }
        out[(b * 5 + a) * O + o] = acc;
    }
}

extern "C" void kernel_launch(void* const* d_in, const int* in_sizes, int n_in,
                              void* d_out, int out_size, void* d_ws, size_t ws_size,
                              hipStream_t stream)
{
    const float* x    = (const float*)d_in[0];
    const float* c0w  = (const float*)d_in[1];
    const float* c0b  = (const float*)d_in[2];
    const float* p0   = (const float*)d_in[3];
    const float* c1w  = (const float*)d_in[4];
    const float* c1b  = (const float*)d_in[5];
    const float* p1   = (const float*)d_in[6];
    const float* c2w  = (const float*)d_in[7];
    const float* c2b  = (const float*)d_in[8];
    const float* p2   = (const float*)d_in[9];
    const float* c3w  = (const float*)d_in[10];
    const float* c3b  = (const float*)d_in[11];
    const float* p3   = (const float*)d_in[12];
    const float* f1w  = (const float*)d_in[13];
    const float* f1b  = (const float*)d_in[14];
    const float* p4   = (const float*)d_in[15];
    const float* f2w  = (const float*)d_in[16];
    const float* f2b  = (const float*)d_in[17];
    const float* p5   = (const float*)d_in[18];
    const float* f3w  = (const float*)d_in[19];
    const float* f3b  = (const float*)d_in[20];

    char* ws = (char*)d_ws;
    ushort* hi0  = (ushort*)(ws);                         // 33,930,240 el f16
    ushort* hi1  = (ushort*)(ws + 67860480);              // 32,501,760 el f16
    float*  P2   = (float*) (ws + 132864000);             //  3,717,120 el
    float*  P3   = (float*) (ws + 147732480);             //    327,680 el
    float*  feat0= (float*) (ws + 149043200);
    float*  feat1= (float*) (ws + 149207040);
    float*  feat2= (float*) (ws + 149288960);
    ushort* Bp0  = (ushort*)(ws + 149329920);             // 19,456 el
    ushort* Bp1  = (ushort*)(ws + 149368832);             // 129,024 el
    int4*   Dt0  = (int4*)  (ws + 149626880);             // 19
    int*    Dt1  = (int*)   (ws + 149627184);             // 126

    // zero halos of hi0/hi1 + all of P2
    hipMemsetAsync(ws, 0, 147732480, stream);

    pack_w0<<<76, 256, 0, stream>>>(c0w, Bp0, Dt0);
    pack_w1<<<504, 256, 0, stream>>>(c1w, Bp1, Dt1);
    pad_input_kernel<<<(7290000 + 255) / 256, 256, 0, stream>>>(x, hi0);

    conv0_mfma<<<dim3(231, 1, 80), 256, 0, stream>>>(hi0, Bp0, Dt0,
                                                     c0b, p0, hi1);
    conv1_mfma<<<dim3(27, 1, 80), 256, 0, stream>>>(hi1, Bp1, Dt1,
                                                    c1b, p1, P2);

    conv_pool_kernel<32, 4, 11, 12, 1452, 4, 1, 4, 0>
        <<<dim3(1, 64, 80), dim3(64), 0, stream>>>(P2, c2w, c2b, p2, P3, 1.f);

    conv3_kernel<<<dim3(160), dim3(256), 0, stream>>>(P3, c3w, c3b, p3, feat0);

    comm_fc_kernel<512, 256, true>
        <<<dim3(5, 16), dim3(256), 0, stream>>>(feat0, f1w, f1b, p4, feat1);
    comm_fc_kernel<256, 128, true>
        <<<dim3(5, 16), dim3(256), 0, stream>>>(feat1, f2w, f2b, p5, feat2);
    comm_fc_kernel<128, 6, false>
        <<<dim3(5, 16), dim3(64), 0, stream>>>(feat2, f3w, f3b, nullptr, (float*)d_out);
}

// Round 4
// 1022.102 us; speedup vs baseline: 1.6338x; 1.2871x over previous
//
#include <hip/hip_runtime.h>

// ---------------------------------------------------------------------------
// CommNet round 12: conv2 -> MFMA implicit GEMM (3-term hi/lo, fp32-equiv).
//  R11 counters: conv2 (conv_pool_kernel) is now the top dispatch: 394us,
//  MfmaUtil 0, VALUBusy 23.8, HBM 2% -> latency-bound scalar conv ignoring
//  the matrix pipe (10.7 GFLOP -> 68us ideal even on VALU).
//  Fix: GEMM view M=80*512 spatial, N=64 oc, K=32ic*64taps=2048.
//   - conv1 epilogue now stores P2 as f16 hi/lo NDHWC [80][11][11][12][32]
//     (hi+lo carries ~24 bits: no new quantization vs fp32 -> absmax stable)
//   - weights packed hi/lo; 3-term MFMA AhBh + AlBh + AhBl (err ~2^-23)
//   - block=(n,z-pair): 4 waves x 2 m-tiles (oy-pairs), pool via LDS
//   - loop shape copied from R11 conv0 (PF=2, branch-free, no pins): that
//     shape neither collapsed (R9 disease) nor spilled (R10 disease).
// Layouts (HW-verified): A[m=lane&15][k=q*8+j], B[n=lane&15][k=q*8+j],
//  D col=lane&15 (=oc), row=q*4+reg (=spatial m).
// ---------------------------------------------------------------------------

typedef __attribute__((ext_vector_type(8)))  _Float16 f16x8;
typedef __attribute__((ext_vector_type(8), aligned(8))) _Float16 f16x8u; // 8B-aligned 16B load
typedef __attribute__((ext_vector_type(4)))  float f32x4;

__device__ __forceinline__ ushort f2h(float f) {
    union { _Float16 h; ushort u; } v;
    v.h = (_Float16)f;                       // v_cvt_f16_f32, RNE
    return v.u;
}
__device__ __forceinline__ float h2f(ushort h) {
    union { ushort u; _Float16 h; } v; v.u = h;
    return (float)v.h;
}

#define MFMA16(A, B, C) __builtin_amdgcn_mfma_f32_16x16x32_f16(A, B, C, 0, 0, 0)

// ---- prep: x [80][4][45^3] fp32 -> hi0 NDHWC padded [80][47][47][48][4] f16
__global__ void pad_input_kernel(const float* __restrict__ x,
                                 ushort* __restrict__ hi)
{
    int t = blockIdx.x * 256 + threadIdx.x;
    const int TOT = 80 * 45 * 45 * 45;
    if (t >= TOT) return;
    int xi = t % 45, r = t / 45;
    int y = r % 45; r /= 45;
    int z = r % 45; int n = r / 45;
    int ib = ((n * 4) * 91125) + z * 2025 + y * 45 + xi;
    int ob = (((n * 47 + z + 1) * 47 + y + 1) * 48 + xi + 1) * 4;
    ushort h4[4];
    #pragma unroll
    for (int ic = 0; ic < 4; ++ic) {
        float v = x[ib + ic * 91125] * (1.f / 255.f);
        h4[ic] = f2h(v);
    }
    *(ushort4*)(hi + ob) = *(ushort4*)h4;
}

// ---- pack conv0 weights [32][4][5][5][5] -> Bp0[19 s][2 ot][64 lane][8 j] f16
__global__ void pack_w0(const float* __restrict__ w, ushort* __restrict__ Bp,
                        int4* __restrict__ Dt)
{
    int t = blockIdx.x * 256 + threadIdx.x;
    if (t < 19 * 2 * 64 * 8) {
        int j = t & 7, l = (t >> 3) & 63, ot = (t >> 9) & 1, s = t >> 10;
        int oc = ot * 16 + (l & 15);
        int k = 32 * s + ((l >> 4) << 3) + j;
        float v = 0.f;
        if (k < 600) {
            int ic = k & 3, t6 = k >> 2;
            int kx = t6 % 6, q = t6 / 6, ky = q % 5, kz = q / 5;
            if (kx < 5) v = w[(oc * 4 + ic) * 125 + kz * 25 + ky * 5 + kx];
        }
        Bp[t] = f2h(v);
    }
    if (t < 19) {
        int dd[4];
        #pragma unroll
        for (int q = 0; q < 4; ++q) {
            int k = 32 * t + 8 * q;
            if (k < 600) {
                int t6 = k >> 2;
                int kx = t6 % 6, qq = t6 / 6;
                dd[q] = (((qq / 5) * 47 + (qq % 5)) * 48 + kx) * 4;  // x-unit=4
            } else dd[q] = 0;
        }
        int4 d; d.x = dd[0]; d.y = dd[1]; d.z = dd[2]; d.w = dd[3];
        Dt[t] = d;
    }
}

// ---- pack conv1 weights [32][32][5][5][5] -> Bp1[126 s][2 ot][64][8] f16
__global__ void pack_w1(const float* __restrict__ w, ushort* __restrict__ Bp,
                        int* __restrict__ Dt)
{
    int t = blockIdx.x * 256 + threadIdx.x;
    if (t < 126 * 2 * 64 * 8) {
        int j = t & 7, l = (t >> 3) & 63, ot = (t >> 9) & 1, s = t >> 10;
        int oc = ot * 16 + (l & 15);
        int ic = ((l >> 4) << 3) + j;
        Bp[t] = (s < 125) ? f2h(w[(oc * 32 + ic) * 125 + s]) : (ushort)0;
    }
    if (t < 126) {
        if (t < 125) {
            int kz = t / 25, ky = (t / 5) % 5, kx = t % 5;
            Dt[t] = ((kz * 23 + ky) * 24 + kx) * 32;                 // x-unit=32
        } else Dt[t] = 0;
    }
}

// ---- pack conv2 weights [64][32][4][4][4] -> Bp2h/Bp2l[64 s][4 nt][64 l][8 j]
// step s = tap: kz=s>>4, ky=(s>>2)&3, kx=s&3; k = s*32 + ic, ic = q*8+j.
__global__ void pack_w2(const float* __restrict__ w,
                        ushort* __restrict__ Bh, ushort* __restrict__ Bl,
                        int* __restrict__ Dt)
{
    int t = blockIdx.x * 256 + threadIdx.x;
    if (t < 64 * 4 * 64 * 8) {
        int j = t & 7, l = (t >> 3) & 63, nt = (t >> 9) & 3, s = t >> 11;
        int oc = nt * 16 + (l & 15);
        int ic = ((l >> 4) << 3) + j;
        int kz = s >> 4, ky = (s >> 2) & 3, kx = s & 3;
        float v = w[(oc * 32 + ic) * 64 + kz * 16 + ky * 4 + kx];
        ushort h = f2h(v);
        Bh[t] = h;
        Bl[t] = f2h(v - h2f(h));
    }
    if (t < 64) {
        int kz = t >> 4, ky = (t >> 2) & 3, kx = t & 3;
        Dt[t] = ((kz * 11 + ky) * 12 + kx) * 32;                     // x-unit=32
    }
}

// ---- conv0 MFMA: hi0 [80][47][47][48][4] f16 -> hi1 [80][23][23][24][32] f16
__global__ __launch_bounds__(256, 2)
void conv0_mfma(const ushort* __restrict__ hi0,
                const ushort* __restrict__ Bp, const int4* __restrict__ Dt,
                const float* __restrict__ bias, const float* __restrict__ slope,
                ushort* __restrict__ hi1)
{
    const int n   = blockIdx.z;
    const int pz  = blockIdx.x / 11, pyg = blockIdx.x % 11;
    const int tid = threadIdx.x, lane = tid & 63, w = tid >> 6;
    const int dz  = w >> 1, pyl = w & 1;
    const int py  = 2 * pyg + pyl;            // may be 21 (invalid, pyg==10)
    const int l15 = lane & 15, q = lane >> 4;

    __shared__ float pool[2][2][21][32];      // [dz][pyl][px][oc]
    __shared__ __align__(16) ushort Bl[19 * 2 * 64 * 8];   // 38912 B

    {   // stage all B into LDS once (2432 x 16B)
        const uint4* src = (const uint4*)Bp;
        uint4* dst = (uint4*)Bl;
        for (int i = tid; i < 2432; i += 256) dst[i] = src[i];
    }

    const int z0 = 2 * pz + dz;
    const int y0 = 2 * py;                    // dy=0 row; dy=1 via +192 els
    const float sl = slope[0];

    int ab[3];
    #pragma unroll
    for (int xt = 0; xt < 3; ++xt) {
        int x = xt * 16 + l15;
        int xr = x > 41 ? 41 : x;
        ab[xt] = (((n * 47 + z0) * 47 + y0) * 48 + xr) * 4;
    }

    f32x4 acc[2][3][2] = {};                  // [dy][xt][ot]
    const f16x8* BL = (const f16x8*)Bl;

    f16x8 avd[2][3][2];                       // [j][xt][dy]

    auto LOADS = [&](int s, int j) {
        int4 dd = Dt[s];
        int delta = q == 0 ? dd.x : q == 1 ? dd.y : q == 2 ? dd.z : dd.w;
        #pragma unroll
        for (int xt = 0; xt < 3; ++xt) {
            int vo = ab[xt] + delta;
            avd[j][xt][0] = *(const f16x8u*)(hi0 + vo);
            avd[j][xt][1] = *(const f16x8u*)(hi0 + vo + 192);  // dy=1: +1 y-row
        }
    };
    auto COMP = [&](int s, int j) {
        f16x8 b0 = BL[(2 * s) * 64 + lane];
        f16x8 b1 = BL[(2 * s + 1) * 64 + lane];
        #pragma unroll
        for (int xt = 0; xt < 3; ++xt)
            #pragma unroll
            for (int dy = 0; dy < 2; ++dy) {
                acc[dy][xt][0] = MFMA16(avd[j][xt][dy], b0, acc[dy][xt][0]);
                acc[dy][xt][1] = MFMA16(avd[j][xt][dy], b1, acc[dy][xt][1]);
            }
    };

    __syncthreads();                          // B staged

    LOADS(0, 0); LOADS(1, 1);
    for (int s = 0; s < 16; s += 2) {         // branch-free body
        COMP(s, 0);     LOADS(s + 2, 0);
        COMP(s + 1, 1); LOADS(s + 3, 1);      // max s+3 = 17
    }
    COMP(16, 0); LOADS(18, 0);
    COMP(17, 1);
    COMP(18, 0);

    #pragma unroll
    for (int xt = 0; xt < 3; ++xt)
        #pragma unroll
        for (int ot = 0; ot < 2; ++ot) {
            float m0 = fmaxf(acc[0][xt][ot][0], acc[1][xt][ot][0]);
            float m1 = fmaxf(acc[0][xt][ot][1], acc[1][xt][ot][1]);
            float m2 = fmaxf(acc[0][xt][ot][2], acc[1][xt][ot][2]);
            float m3 = fmaxf(acc[0][xt][ot][3], acc[1][xt][ot][3]);
            int pxe = xt * 8 + 2 * q, pxo = pxe + 1;
            if (pxe < 21) pool[dz][pyl][pxe][ot * 16 + l15] = fmaxf(m0, m1);
            if (pxo < 21) pool[dz][pyl][pxo][ot * 16 + l15] = fmaxf(m2, m3);
        }
    __syncthreads();

    for (int t2 = tid; t2 < 1344; t2 += 256) {
        int oc = t2 & 31, r = t2 >> 5;
        int px = r % 21, pyl2 = r / 21;
        int py2 = 2 * pyg + pyl2;
        if (py2 > 20) continue;
        float v = fmaxf(pool[0][pyl2][px][oc], pool[1][pyl2][px][oc]);
        v += bias[oc];
        v = (v >= 0.f) ? v : sl * v;
        int o = (((n * 23 + pz + 1) * 23 + py2 + 1) * 24 + px + 1) * 32 + oc;
        hi1[o] = f2h(v);
    }
}

// ---- conv1 MFMA: hi1 [80][23][23][24][32] f16 -> P2h/P2l f16 NDHWC padded
// [80][11][11][12][32]; hi/lo pair keeps conv2 input at ~fp32 precision.
__global__ __launch_bounds__(256)
void conv1_mfma(const ushort* __restrict__ hi1,
                const ushort* __restrict__ Bp, const int* __restrict__ Dt,
                const float* __restrict__ bias, const float* __restrict__ slope,
                ushort* __restrict__ P2h, ushort* __restrict__ P2l)
{
    const int n   = blockIdx.z;
    const int pz  = blockIdx.x / 3, pyg = blockIdx.x % 3;
    const int tid = threadIdx.x, lane = tid & 63, w = tid >> 6;
    const int dz = w >> 1, dy = w & 1;
    const int q = lane >> 4, l15 = lane & 15;

    __shared__ float pool[4][27][32];
    const int z0 = 2 * pz + dz;

    int ab[4];
    #pragma unroll
    for (int t = 0; t < 4; ++t) {
        int flat = t * 16 + l15;
        if (flat > 53) flat = 53;
        int pyl = flat / 18, x = flat - pyl * 18;
        int y0 = 2 * (pyg * 3 + pyl) + dy;
        ab[t] = ((((n * 23 + z0) * 23 + y0) * 24 + x) << 5) + q * 8;
    }

    f32x4 acc[4][2] = {};
    const f16x8* Bv = (const f16x8*)Bp;

    f16x8 ahv[3][4], b0v[3], b1v[3];

    auto LOADS = [&](int s, int j) {
        int off = Dt[s];
        b0v[j] = Bv[(2 * s) * 64 + lane];
        b1v[j] = Bv[(2 * s + 1) * 64 + lane];
        #pragma unroll
        for (int t = 0; t < 4; ++t)
            ahv[j][t] = *(const f16x8*)(hi1 + ab[t] + off);    // 16B aligned
    };
    auto COMP = [&](int j) {
        #pragma unroll
        for (int t = 0; t < 4; ++t) {
            acc[t][0] = MFMA16(ahv[j][t], b0v[j], acc[t][0]);
            acc[t][1] = MFMA16(ahv[j][t], b1v[j], acc[t][1]);
        }
    };

    LOADS(0, 0); LOADS(1, 1);
    for (int s = 0; s < 123; s += 3) {        // branch-free: loads to s+4<=124
        LOADS(s + 2, 2); COMP(0);
        LOADS(s + 3, 0); COMP(1);
        LOADS(s + 4, 1); COMP(2);
    }
    LOADS(125, 2);                            // buf0=123, buf1=124 already loaded
    COMP(0); COMP(1); COMP(2);

    #pragma unroll
    for (int t = 0; t < 4; ++t) {
        int p0 = t * 8 + q * 2;
        float e0 = fmaxf(acc[t][0][0], acc[t][0][1]);
        float o0 = fmaxf(acc[t][0][2], acc[t][0][3]);
        float e1 = fmaxf(acc[t][1][0], acc[t][1][1]);
        float o1 = fmaxf(acc[t][1][2], acc[t][1][3]);
        if (p0 < 27)     { pool[w][p0][l15] = e0;     pool[w][p0][16 + l15] = e1; }
        if (p0 + 1 < 27) { pool[w][p0 + 1][l15] = o0; pool[w][p0 + 1][16 + l15] = o1; }
    }
    __syncthreads();

    for (int t2 = tid; t2 < 864; t2 += 256) {
        int oc = t2 & 31, pr = t2 >> 5;          // pr = pyl*9 + px
        int pyl = pr / 9, px = pr % 9;
        float v = fmaxf(fmaxf(pool[0][pr][oc], pool[1][pr][oc]),
                        fmaxf(pool[2][pr][oc], pool[3][pr][oc]));
        v += bias[oc];
        float s0 = slope[0];
        v = (v >= 0.f) ? v : s0 * v;
        int py = pyg * 3 + pyl;
        int o = (((n * 11 + pz + 1) * 11 + py + 1) * 12 + px + 1) * 32 + oc;
        ushort h = f2h(v);
        P2h[o] = h;
        P2l[o] = f2h(v - h2f(h));
    }
}

// ---- conv2 MFMA: P2h/P2l [80][11][11][12][32] -> pool -> P3 fp32 [n][64][64]
// block = (n, zq): oz in {2zq, 2zq+1}; M=128 = 8 m-tiles (ozl, oy-pair);
// wave w: tiles {2w, 2w+1}: ozl=w>>1, oyp = 2*(w&1)+ti. N=64 = 4 n-tiles.
// K = 64 taps x 32 ic; 3-term hi/lo MFMA (fp32-equivalent).
__global__ __launch_bounds__(256)
void conv2_mfma(const ushort* __restrict__ P2h, const ushort* __restrict__ P2l,
                const ushort* __restrict__ Bph, const ushort* __restrict__ Bpl,
                const int* __restrict__ Dt,
                const float* __restrict__ bias, const float* __restrict__ slope,
                float* __restrict__ P3)
{
    const int n  = blockIdx.x >> 2, zq = blockIdx.x & 3;
    const int tid = threadIdx.x, lane = tid & 63, w = tid >> 6;
    const int q = lane >> 4, l15 = lane & 15;

    __shared__ float pool[2][2][4][4][64];    // [my][ozl][py][px][oc] 16 KB

    const int ozl = w >> 1, oyp0 = 2 * (w & 1);
    const int oz  = zq * 2 + ozl;             // output z (padded coord base)
    const int myA = l15 >> 3, mxA = l15 & 7;  // A-operand m = l15

    int ab[2];
    ab[0] = (((n * 11 + oz) * 11 + oyp0 * 2 + myA) * 12 + mxA) * 32 + q * 8;
    ab[1] = ab[0] + 2 * 12 * 32;              // next oy-pair (+2 y rows)

    f32x4 acc[2][4] = {};                     // [ti][nt]
    const f16x8* BH = (const f16x8*)Bph;
    const f16x8* BL = (const f16x8*)Bpl;

    f16x8 ahv[2][2], alv[2][2], bhv[2][4], blv[2][4];

    auto LOADS = [&](int s, int j) {
        int d = Dt[s];
        #pragma unroll
        for (int t = 0; t < 2; ++t) {
            ahv[j][t] = *(const f16x8u*)(P2h + ab[t] + d);
            alv[j][t] = *(const f16x8u*)(P2l + ab[t] + d);
        }
        #pragma unroll
        for (int nt = 0; nt < 4; ++nt) {
            bhv[j][nt] = BH[(s * 4 + nt) * 64 + lane];
            blv[j][nt] = BL[(s * 4 + nt) * 64 + lane];
        }
    };
    auto COMP = [&](int j) {
        #pragma unroll
        for (int t = 0; t < 2; ++t)
            #pragma unroll
            for (int nt = 0; nt < 4; ++nt) {
                acc[t][nt] = MFMA16(ahv[j][t], bhv[j][nt], acc[t][nt]);
                acc[t][nt] = MFMA16(alv[j][t], bhv[j][nt], acc[t][nt]);
                acc[t][nt] = MFMA16(ahv[j][t], blv[j][nt], acc[t][nt]);
            }
    };

    LOADS(0, 0); LOADS(1, 1);
    for (int s = 0; s < 62; s += 2) {         // branch-free body
        COMP(0); LOADS(s + 2, 0);
        COMP(1); LOADS(s + 3, 1);             // max s+3 = 63
    }
    COMP(0); COMP(1);

    // D row m = q*4+reg: my = q>>1, mx = (q&1)*4+reg; x-pool pairs (r0,r1),(r2,r3)
    const int myD = q >> 1, pxe = (q & 1) * 2;
    #pragma unroll
    for (int t = 0; t < 2; ++t) {
        int py = oyp0 + t;
        #pragma unroll
        for (int nt = 0; nt < 4; ++nt) {
            int oc = nt * 16 + l15;
            pool[myD][ozl][py][pxe][oc]     = fmaxf(acc[t][nt][0], acc[t][nt][1]);
            pool[myD][ozl][py][pxe + 1][oc] = fmaxf(acc[t][nt][2], acc[t][nt][3]);
        }
    }
    __syncthreads();

    for (int t2 = tid; t2 < 1024; t2 += 256) {
        int oc = t2 & 63, r = t2 >> 6;
        int py = r >> 2, px = r & 3;
        float v = fmaxf(fmaxf(pool[0][0][py][px][oc], pool[0][1][py][px][oc]),
                        fmaxf(pool[1][0][py][px][oc], pool[1][1][py][px][oc]));
        v += bias[oc];
        float a = slope[0];
        v = (v >= 0.f) ? v : a * v;
        P3[((long)n * 64 + oc) * 64 + zq * 16 + py * 4 + px] = v;
    }
}

// ---- conv3 (fp32 direct) ----
__global__ void conv3_kernel(const float* __restrict__ in,
                             const float* __restrict__ w,
                             const float* __restrict__ bias,
                             const float* __restrict__ slope,
                             float* __restrict__ out)
{
    int idx = blockIdx.x * blockDim.x + threadIdx.x;
    const int TOTAL = 80 * 64 * 8;
    if (idx >= TOTAL) return;
    int p  = idx & 7;
    int oc = (idx >> 3) & 63;
    int n  = idx >> 9;
    int ox = p & 1, oy = (p >> 1) & 1, oz = p >> 2;

    const float* inb = in + (long)n * 64 * 64;
    const float* wb  = w + (long)oc * 64 * 27;

    float acc = 0.f;
    for (int ic = 0; ic < 64; ++ic) {
        const float* inc = inb + ic * 64;
        const float* wc  = wb + ic * 27;
        #pragma unroll
        for (int kz = 0; kz < 3; ++kz)
            #pragma unroll
            for (int ky = 0; ky < 3; ++ky)
                #pragma unroll
                for (int kx = 0; kx < 3; ++kx)
                    acc += wc[(kz * 3 + ky) * 3 + kx] *
                           inc[((oz + kz) * 4 + (oy + ky)) * 4 + (ox + kx)];
    }
    float v = acc + bias[oc];
    float a = slope[0];
    v = (v >= 0.f) ? v : a * v;
    out[idx] = v;
}

// ---- comm-FC ----
template<int D, int O, bool PRELU_ON>
__global__ void comm_fc_kernel(const float* __restrict__ feat,
                               const float* __restrict__ w,
                               const float* __restrict__ bias,
                               const float* __restrict__ slope,
                               float* __restrict__ out)
{
    const int a = blockIdx.x;
    const int b = blockIdx.y;

    __shared__ __align__(16) float cat[2 * D];
    for (int i = threadIdx.x; i < D; i += blockDim.x) {
        float m = 0.f;
        #pragma unroll
        for (int aa = 0; aa < 5; ++aa) m += feat[(b * 5 + aa) * D + i];
        cat[i]     = feat[(b * 5 + a) * D + i];
        cat[D + i] = m * 0.2f;
    }
    __syncthreads();

    for (int o = threadIdx.x; o < O; o += blockDim.x) {
        const float4* wr = (const float4*)(w + ((long)(a * O) + o) * 2 * D);
        const float4* cr = (const float4*)cat;
        float acc = 0.f;
        for (int i = 0; i < 2 * D / 4; ++i) {
            float4 wv = wr[i];
            float4 cv = cr[i];
            acc += wv.x * cv.x + wv.y * cv.y + wv.z * cv.z + wv.w * cv.w;
        }
        acc += bias[a * O + o];
        if constexpr (PRELU_ON) {
            float s = slope[0];
            acc = (acc >= 0.f) ? acc : s * acc;
        }
        out[(b * 5 + a) * O + o] = acc;
    }
}

extern "C" void kernel_launch(void* const* d_in, const int* in_sizes, int n_in,
                              void* d_out, int out_size, void* d_ws, size_t ws_size,
                              hipStream_t stream)
{
    const float* x    = (const float*)d_in[0];
    const float* c0w  = (const float*)d_in[1];
    const float* c0b  = (const float*)d_in[2];
    const float* p0   = (const float*)d_in[3];
    const float* c1w  = (const float*)d_in[4];
    const float* c1b  = (const float*)d_in[5];
    const float* p1   = (const float*)d_in[6];
    const float* c2w  = (const float*)d_in[7];
    const float* c2b  = (const float*)d_in[8];
    const float* p2   = (const float*)d_in[9];
    const float* c3w  = (const float*)d_in[10];
    const float* c3b  = (const float*)d_in[11];
    const float* p3   = (const float*)d_in[12];
    const float* f1w  = (const float*)d_in[13];
    const float* f1b  = (const float*)d_in[14];
    const float* p4   = (const float*)d_in[15];
    const float* f2w  = (const float*)d_in[16];
    const float* f2b  = (const float*)d_in[17];
    const float* p5   = (const float*)d_in[18];
    const float* f3w  = (const float*)d_in[19];
    const float* f3b  = (const float*)d_in[20];

    char* ws = (char*)d_ws;
    ushort* hi0  = (ushort*)(ws);                         // 33,930,240 el f16
    ushort* hi1  = (ushort*)(ws + 67860480);              // 32,501,760 el f16
    ushort* P2h  = (ushort*)(ws + 132864000);             //  3,717,120 el f16
    ushort* P2l  = (ushort*)(ws + 140298240);             //  3,717,120 el f16
    float*  P3   = (float*) (ws + 147732480);             //    327,680 el
    float*  feat0= (float*) (ws + 149043200);
    float*  feat1= (float*) (ws + 149207040);
    float*  feat2= (float*) (ws + 149288960);
    ushort* Bp0  = (ushort*)(ws + 149329920);             // 19,456 el
    ushort* Bp1  = (ushort*)(ws + 149368832);             // 129,024 el
    int4*   Dt0  = (int4*)  (ws + 149626880);             // 19
    int*    Dt1  = (int*)   (ws + 149627184);             // 126
    ushort* Bp2h = (ushort*)(ws + 149700000);             // 131,072 el
    ushort* Bp2l = (ushort*)(ws + 149962144);             // 131,072 el
    int*    Dt2  = (int*)   (ws + 150224288);             // 64

    // zero halos of hi0/hi1 + all of P2h/P2l
    hipMemsetAsync(ws, 0, 147732480, stream);

    pack_w0<<<76, 256, 0, stream>>>(c0w, Bp0, Dt0);
    pack_w1<<<504, 256, 0, stream>>>(c1w, Bp1, Dt1);
    pack_w2<<<512, 256, 0, stream>>>(c2w, Bp2h, Bp2l, Dt2);
    pad_input_kernel<<<(7290000 + 255) / 256, 256, 0, stream>>>(x, hi0);

    conv0_mfma<<<dim3(231, 1, 80), 256, 0, stream>>>(hi0, Bp0, Dt0,
                                                     c0b, p0, hi1);
    conv1_mfma<<<dim3(27, 1, 80), 256, 0, stream>>>(hi1, Bp1, Dt1,
                                                    c1b, p1, P2h, P2l);
    conv2_mfma<<<dim3(320), 256, 0, stream>>>(P2h, P2l, Bp2h, Bp2l, Dt2,
                                              c2b, p2, P3);

    conv3_kernel<<<dim3(160), dim3(256), 0, stream>>>(P3, c3w, c3b, p3, feat0);

    comm_fc_kernel<512, 256, true>
        <<<dim3(5, 16), dim3(256), 0, stream>>>(feat0, f1w, f1b, p4, feat1);
    comm_fc_kernel<256, 128, true>
        <<<dim3(5, 16), dim3(256), 0, stream>>>(feat1, f2w, f2b, p5, feat2);
    comm_fc_kernel<128, 6, false>
        <<<dim3(5, 16), dim3(64), 0, stream>>>(feat2, f3w, f3b, nullptr, (float*)d_out);
}

// Round 6
// 861.972 us; speedup vs baseline: 1.9373x; 1.1858x over previous
//
#include <hip/hip_runtime.h>

// ---------------------------------------------------------------------------
// CommNet round 14: R13 (A-footprint in LDS) with the staging index FIXED.
//  R13 failed absmax 4.2e-2: conv0 staging src had a double-subtracted zr
//  term (base + zr*9024 + rem*4 - zr*1536; rem already excludes zr) ->
//  staged A for kz>=1 taps was the wrong y/z rows. Fix: src = base +
//  zr*9024 + rem*4. Everything else identical to R13 for attribution.
//  Design (R13): conv0 stages 18KB A once/block (22x dedup), per-step A =
//  6 ds_reads (LDS pipe) + B = 2 globals (L1 pipe); conv1 rings 3 z-slices
//  (45KB) phased over kz, T14 async stage; pad_input writes hi0 halos.
// Layouts (HW-verified): A[m=lane&15][k=q*8+j], B[n=lane&15][k=q*8+j],
//  D col=lane&15, row=q*4+reg.
// ---------------------------------------------------------------------------

typedef __attribute__((ext_vector_type(8)))  _Float16 f16x8;
typedef __attribute__((ext_vector_type(8), aligned(8))) _Float16 f16x8u; // 8B-aligned 16B access
typedef __attribute__((ext_vector_type(4)))  float f32x4;

__device__ __forceinline__ ushort f2h(float f) {
    union { _Float16 h; ushort u; } v;
    v.h = (_Float16)f;                       // v_cvt_f16_f32, RNE
    return v.u;
}
__device__ __forceinline__ float h2f(ushort h) {
    union { ushort u; _Float16 h; } v; v.u = h;
    return (float)v.h;
}

#define MFMA16(A, B, C) __builtin_amdgcn_mfma_f32_16x16x32_f16(A, B, C, 0, 0, 0)

// ---- prep: x [80][4][45^3] fp32 -> hi0 NDHWC padded [80][47][47][48][4] f16
// Covers the FULL padded volume (halos written as zeros -> no memset).
__global__ void pad_input_kernel(const float* __restrict__ x,
                                 ushort* __restrict__ hi)
{
    int t = blockIdx.x * 256 + threadIdx.x;
    const int TOT = 80 * 47 * 47 * 48;
    if (t >= TOT) return;
    int xo = t % 48, r = t / 48;
    int yo = r % 47; r /= 47;
    int zo = r % 47; int n = r / 47;
    ushort h4[4] = {0, 0, 0, 0};
    if (zo >= 1 && zo <= 45 && yo >= 1 && yo <= 45 && xo >= 1 && xo <= 45) {
        int ib = n * 4 * 91125 + (zo - 1) * 2025 + (yo - 1) * 45 + (xo - 1);
        #pragma unroll
        for (int ic = 0; ic < 4; ++ic)
            h4[ic] = f2h(x[ib + ic * 91125] * (1.f / 255.f));
    }
    *(ushort4*)(hi + t * 4) = *(ushort4*)h4;
}

// ---- pack conv0 weights [32][4][5][5][5] -> Bp0[19 s][2 ot][64 lane][8 j] f16
// k = ((kz*5+ky)*6+kx)*4 + ic  (kx in [0,6), kx==5 zero; K=600, 19 steps = 608)
// DtL: per-step int4 of LDS deltas (per q): (kz*8+ky)*192 + kx*4.
__global__ void pack_w0(const float* __restrict__ w, ushort* __restrict__ Bp,
                        int4* __restrict__ DtL)
{
    int t = blockIdx.x * 256 + threadIdx.x;
    if (t < 19 * 2 * 64 * 8) {
        int j = t & 7, l = (t >> 3) & 63, ot = (t >> 9) & 1, s = t >> 10;
        int oc = ot * 16 + (l & 15);
        int k = 32 * s + ((l >> 4) << 3) + j;
        float v = 0.f;
        if (k < 600) {
            int ic = k & 3, t6 = k >> 2;
            int kx = t6 % 6, q = t6 / 6, ky = q % 5, kz = q / 5;
            if (kx < 5) v = w[(oc * 4 + ic) * 125 + kz * 25 + ky * 5 + kx];
        }
        Bp[t] = f2h(v);
    }
    if (t < 19) {
        int dd[4];
        #pragma unroll
        for (int q = 0; q < 4; ++q) {
            int k = 32 * t + 8 * q;
            if (k < 600) {
                int t6 = k >> 2;
                int kx = t6 % 6, qq = t6 / 6;
                dd[q] = ((qq / 5) * 8 + (qq % 5)) * 192 + kx * 4;    // LDS els
            } else dd[q] = 0;
        }
        int4 d; d.x = dd[0]; d.y = dd[1]; d.z = dd[2]; d.w = dd[3];
        DtL[t] = d;
    }
}

// ---- pack conv1 weights [32][32][5][5][5] -> Bp1[126 s][2 ot][64][8] f16
// step s = tap, kz-major (125 real; slot 125 unused)
__global__ void pack_w1(const float* __restrict__ w, ushort* __restrict__ Bp)
{
    int t = blockIdx.x * 256 + threadIdx.x;
    if (t < 126 * 2 * 64 * 8) {
        int j = t & 7, l = (t >> 3) & 63, ot = (t >> 9) & 1, s = t >> 10;
        int oc = ot * 16 + (l & 15);
        int ic = ((l >> 4) << 3) + j;
        Bp[t] = (s < 125) ? f2h(w[(oc * 32 + ic) * 125 + s]) : (ushort)0;
    }
}

// ---- pack conv2 weights [64][32][4][4][4] -> Bp2h/Bp2l[64 s][4 nt][64 l][8 j]
__global__ void pack_w2(const float* __restrict__ w,
                        ushort* __restrict__ Bh, ushort* __restrict__ Bl,
                        int* __restrict__ Dt)
{
    int t = blockIdx.x * 256 + threadIdx.x;
    if (t < 64 * 4 * 64 * 8) {
        int j = t & 7, l = (t >> 3) & 63, nt = (t >> 9) & 3, s = t >> 11;
        int oc = nt * 16 + (l & 15);
        int ic = ((l >> 4) << 3) + j;
        int kz = s >> 4, ky = (s >> 2) & 3, kx = s & 3;
        float v = w[(oc * 32 + ic) * 64 + kz * 16 + ky * 4 + kx];
        ushort h = f2h(v);
        Bh[t] = h;
        Bl[t] = f2h(v - h2f(h));
    }
    if (t < 64) {
        int kz = t >> 4, ky = (t >> 2) & 3, kx = t & 3;
        Dt[t] = ((kz * 11 + ky) * 12 + kx) * 32;                     // x-unit=32
    }
}

// ---- conv0 MFMA: hi0 [80][47][47][48][4] f16 -> hi1 [80][23][23][24][32] f16
// block = (pz, pyg); waves (dz,pyl); dy-merged. A-footprint staged in LDS:
// As[zr 6][yr 8][x 48 * 4ic] (18KB); B from global (L1 pipe).
__global__ __launch_bounds__(256)
void conv0_mfma(const ushort* __restrict__ hi0,
                const ushort* __restrict__ Bp, const int4* __restrict__ DtL,
                const float* __restrict__ bias, const float* __restrict__ slope,
                ushort* __restrict__ hi1)
{
    const int n   = blockIdx.z;
    const int pz  = blockIdx.x / 11, pyg = blockIdx.x % 11;
    const int tid = threadIdx.x, lane = tid & 63, w = tid >> 6;
    const int dz  = w >> 1, pyl = w & 1;
    const int l15 = lane & 15, q = lane >> 4;

    __shared__ float pool[2][2][21][32];                 // 10.75 KB
    __shared__ __align__(16) ushort As[6 * 8 * 192];     // 18 KB

    {   // stage A footprint: z [2pz,2pz+6), y [4pyg,4pyg+8), x [0,48)*4ic
        const int base = ((n * 47 + 2 * pz) * 47 + 4 * pyg) * 192;
        for (int u = tid; u < 2304; u += 256) {          // 8B units (4 els)
            int zr = u / 384, rem = u - zr * 384;        // rem = yr*48 + xu
            int src = base + zr * 9024 + rem * 4;        // (zr*47+yr)*192+xu*4  [R14 FIX]
            *(uint2*)(As + u * 4) = *(const uint2*)(hi0 + src);
        }
    }

    const float sl = slope[0];
    int lb[3];
    #pragma unroll
    for (int xt = 0; xt < 3; ++xt) {
        int x = xt * 16 + l15;
        int xr = x > 41 ? 41 : x;
        lb[xt] = (dz * 8 + 2 * pyl) * 192 + xr * 4;
    }

    f32x4 acc[2][3][2] = {};                  // [dy][xt][ot]
    const f16x8* Bv = (const f16x8*)Bp;
    f16x8 avd[2][3][2], b0v[2], b1v[2];       // [j][xt][dy]

    auto LOADS = [&](int s, int j) {
        int4 dd = DtL[s];
        int delta = q == 0 ? dd.x : q == 1 ? dd.y : q == 2 ? dd.z : dd.w;
        b0v[j] = Bv[(2 * s) * 64 + lane];
        b1v[j] = Bv[(2 * s + 1) * 64 + lane];
        #pragma unroll
        for (int xt = 0; xt < 3; ++xt) {
            const ushort* p = As + lb[xt] + delta;
            avd[j][xt][0] = *(const f16x8u*)p;
            avd[j][xt][1] = *(const f16x8u*)(p + 192);   // dy=1: +1 y-row
        }
    };
    auto COMP = [&](int j) {
        #pragma unroll
        for (int xt = 0; xt < 3; ++xt)
            #pragma unroll
            for (int dy = 0; dy < 2; ++dy) {
                acc[dy][xt][0] = MFMA16(avd[j][xt][dy], b0v[j], acc[dy][xt][0]);
                acc[dy][xt][1] = MFMA16(avd[j][xt][dy], b1v[j], acc[dy][xt][1]);
            }
    };

    __syncthreads();                          // A staged

    LOADS(0, 0); LOADS(1, 1);
    for (int s = 0; s < 16; s += 2) {         // branch-free body
        COMP(0); LOADS(s + 2, 0);
        COMP(1); LOADS(s + 3, 1);             // max s+3 = 17
    }
    COMP(0); LOADS(18, 0);
    COMP(1);
    COMP(0);

    #pragma unroll
    for (int xt = 0; xt < 3; ++xt)
        #pragma unroll
        for (int ot = 0; ot < 2; ++ot) {
            float m0 = fmaxf(acc[0][xt][ot][0], acc[1][xt][ot][0]);
            float m1 = fmaxf(acc[0][xt][ot][1], acc[1][xt][ot][1]);
            float m2 = fmaxf(acc[0][xt][ot][2], acc[1][xt][ot][2]);
            float m3 = fmaxf(acc[0][xt][ot][3], acc[1][xt][ot][3]);
            int pxe = xt * 8 + 2 * q, pxo = pxe + 1;
            if (pxe < 21) pool[dz][pyl][pxe][ot * 16 + l15] = fmaxf(m0, m1);
            if (pxo < 21) pool[dz][pyl][pxo][ot * 16 + l15] = fmaxf(m2, m3);
        }
    __syncthreads();

    for (int t2 = tid; t2 < 1344; t2 += 256) {
        int oc = t2 & 31, r = t2 >> 5;
        int px = r % 21, pyl2 = r / 21;
        int py2 = 2 * pyg + pyl2;
        if (py2 > 20) continue;
        float v = fmaxf(pool[0][pyl2][px][oc], pool[1][pyl2][px][oc]);
        v += bias[oc];
        v = (v >= 0.f) ? v : sl * v;
        int o = (((n * 23 + pz + 1) * 23 + py2 + 1) * 24 + px + 1) * 32 + oc;
        hi1[o] = f2h(v);
    }
}

// ---- conv1 MFMA: hi1 [80][23][23][24][32] f16 -> P2h/P2l f16 NDHWC padded
// A via LDS ring of 3 z-slices (15.4KB each), phased over kz (5 x 25 steps),
// T14 async stage. B from global. M flat = pyl*18+x (4 tiles of 16).
__global__ __launch_bounds__(256)
void conv1_mfma(const ushort* __restrict__ hi1,
                const ushort* __restrict__ Bp,
                const float* __restrict__ bias, const float* __restrict__ slope,
                ushort* __restrict__ P2h, ushort* __restrict__ P2l)
{
    const int n   = blockIdx.z;
    const int pz  = blockIdx.x / 3, pyg = blockIdx.x % 3;
    const int tid = threadIdx.x, lane = tid & 63, w = tid >> 6;
    const int dz = w >> 1, dy = w & 1;
    const int q = lane >> 4, l15 = lane & 15;

    __shared__ float pool[4][27][32];                    // 13.5 KB
    __shared__ __align__(16) ushort As[3 * 7680];        // 45 KB (3 z-slices)

    int lb[4];
    #pragma unroll
    for (int t = 0; t < 4; ++t) {
        int flat = t * 16 + l15;
        if (flat > 53) flat = 53;
        int pyl = flat / 18, x = flat - pyl * 18;
        lb[t] = (2 * pyl + dy) * 768 + x * 32 + q * 8;
    }

    f16x8 stg[4];
    auto STAGE_LOAD = [&](int zoff) {                    // issue early (T14)
        const ushort* src = hi1 + ((n * 23 + 2 * pz + zoff) * 23 + 6 * pyg) * 768;
        #pragma unroll
        for (int r = 0; r < 4; ++r) {
            int u = tid + r * 256;
            if (u < 960) stg[r] = *(const f16x8*)(src + u * 8);
        }
    };
    auto STAGE_WRITE = [&](int zoff) {                   // write late
        int slot = zoff % 3;
        #pragma unroll
        for (int r = 0; r < 4; ++r) {
            int u = tid + r * 256;
            if (u < 960) *(f16x8*)(As + slot * 7680 + u * 8) = stg[r];
        }
    };

    f32x4 acc[4][2] = {};
    const f16x8* Bv = (const f16x8*)Bp;
    f16x8 ahv[2][4], b0v[2], b1v[2];

    // prologue: slices 0,1
    STAGE_LOAD(0); STAGE_WRITE(0);
    STAGE_LOAD(1); STAGE_WRITE(1);
    __syncthreads();

    for (int kz = 0; kz < 5; ++kz) {
        if (kz < 4) STAGE_LOAD(kz + 2);
        const int slotbase = ((dz + kz) % 3) * 7680;
        const int sg0 = kz * 25;

        auto LOADS = [&](int s, int j) {                 // s in [0,25)
            int delta = (s / 5) * 768 + (s % 5) * 32;
            int sg = sg0 + s;
            b0v[j] = Bv[(2 * sg) * 64 + lane];
            b1v[j] = Bv[(2 * sg + 1) * 64 + lane];
            #pragma unroll
            for (int t = 0; t < 4; ++t)
                ahv[j][t] = *(const f16x8u*)(As + slotbase + lb[t] + delta);
        };
        auto COMP = [&](int j) {
            #pragma unroll
            for (int t = 0; t < 4; ++t) {
                acc[t][0] = MFMA16(ahv[j][t], b0v[j], acc[t][0]);
                acc[t][1] = MFMA16(ahv[j][t], b1v[j], acc[t][1]);
            }
        };

        LOADS(0, 0); LOADS(1, 1);
        for (int s = 0; s < 24; s += 2) {
            COMP(0); LOADS(s + 2 > 24 ? 24 : s + 2, 0);
            COMP(1); LOADS(s + 3 > 24 ? 24 : s + 3, 1);
        }
        COMP(0);                                         // step 24

        __syncthreads();                                 // phase reads done
        if (kz < 4) STAGE_WRITE(kz + 2);
        __syncthreads();                                 // writes visible
    }

    #pragma unroll
    for (int t = 0; t < 4; ++t) {
        int p0 = t * 8 + q * 2;
        float e0 = fmaxf(acc[t][0][0], acc[t][0][1]);
        float o0 = fmaxf(acc[t][0][2], acc[t][0][3]);
        float e1 = fmaxf(acc[t][1][0], acc[t][1][1]);
        float o1 = fmaxf(acc[t][1][2], acc[t][1][3]);
        if (p0 < 27)     { pool[w][p0][l15] = e0;     pool[w][p0][16 + l15] = e1; }
        if (p0 + 1 < 27) { pool[w][p0 + 1][l15] = o0; pool[w][p0 + 1][16 + l15] = o1; }
    }
    __syncthreads();

    for (int t2 = tid; t2 < 864; t2 += 256) {
        int oc = t2 & 31, pr = t2 >> 5;          // pr = pyl*9 + px
        int pyl = pr / 9, px = pr % 9;
        float v = fmaxf(fmaxf(pool[0][pr][oc], pool[1][pr][oc]),
                        fmaxf(pool[2][pr][oc], pool[3][pr][oc]));
        v += bias[oc];
        float s0 = slope[0];
        v = (v >= 0.f) ? v : s0 * v;
        int py = pyg * 3 + pyl;
        int o = (((n * 11 + pz + 1) * 11 + py + 1) * 12 + px + 1) * 32 + oc;
        ushort h = f2h(v);
        P2h[o] = h;
        P2l[o] = f2h(v - h2f(h));
    }
}

// ---- conv2 MFMA: P2h/P2l [80][11][11][12][32] -> pool -> P3 fp32 [n][64][64]
__global__ __launch_bounds__(256)
void conv2_mfma(const ushort* __restrict__ P2h, const ushort* __restrict__ P2l,
                const ushort* __restrict__ Bph, const ushort* __restrict__ Bpl,
                const int* __restrict__ Dt,
                const float* __restrict__ bias, const float* __restrict__ slope,
                float* __restrict__ P3)
{
    const int n  = blockIdx.x >> 2, zq = blockIdx.x & 3;
    const int tid = threadIdx.x, lane = tid & 63, w = tid >> 6;
    const int q = lane >> 4, l15 = lane & 15;

    __shared__ float pool[2][2][4][4][64];    // [my][ozl][py][px][oc] 16 KB

    const int ozl = w >> 1, oyp0 = 2 * (w & 1);
    const int oz  = zq * 2 + ozl;
    const int myA = l15 >> 3, mxA = l15 & 7;

    int ab[2];
    ab[0] = (((n * 11 + oz) * 11 + oyp0 * 2 + myA) * 12 + mxA) * 32 + q * 8;
    ab[1] = ab[0] + 2 * 12 * 32;

    f32x4 acc[2][4] = {};
    const f16x8* BH = (const f16x8*)Bph;
    const f16x8* BL = (const f16x8*)Bpl;

    f16x8 ahv[2][2], alv[2][2], bhv[2][4], blv[2][4];

    auto LOADS = [&](int s, int j) {
        int d = Dt[s];
        #pragma unroll
        for (int t = 0; t < 2; ++t) {
            ahv[j][t] = *(const f16x8u*)(P2h + ab[t] + d);
            alv[j][t] = *(const f16x8u*)(P2l + ab[t] + d);
        }
        #pragma unroll
        for (int nt = 0; nt < 4; ++nt) {
            bhv[j][nt] = BH[(s * 4 + nt) * 64 + lane];
            blv[j][nt] = BL[(s * 4 + nt) * 64 + lane];
        }
    };
    auto COMP = [&](int j) {
        #pragma unroll
        for (int t = 0; t < 2; ++t)
            #pragma unroll
            for (int nt = 0; nt < 4; ++nt) {
                acc[t][nt] = MFMA16(ahv[j][t], bhv[j][nt], acc[t][nt]);
                acc[t][nt] = MFMA16(alv[j][t], bhv[j][nt], acc[t][nt]);
                acc[t][nt] = MFMA16(ahv[j][t], blv[j][nt], acc[t][nt]);
            }
    };

    LOADS(0, 0); LOADS(1, 1);
    for (int s = 0; s < 62; s += 2) {
        COMP(0); LOADS(s + 2, 0);
        COMP(1); LOADS(s + 3, 1);
    }
    COMP(0); COMP(1);

    const int myD = q >> 1, pxe = (q & 1) * 2;
    #pragma unroll
    for (int t = 0; t < 2; ++t) {
        int py = oyp0 + t;
        #pragma unroll
        for (int nt = 0; nt < 4; ++nt) {
            int oc = nt * 16 + l15;
            pool[myD][ozl][py][pxe][oc]     = fmaxf(acc[t][nt][0], acc[t][nt][1]);
            pool[myD][ozl][py][pxe + 1][oc] = fmaxf(acc[t][nt][2], acc[t][nt][3]);
        }
    }
    __syncthreads();

    for (int t2 = tid; t2 < 1024; t2 += 256) {
        int oc = t2 & 63, r = t2 >> 6;
        int py = r >> 2, px = r & 3;
        float v = fmaxf(fmaxf(pool[0][0][py][px][oc], pool[0][1][py][px][oc]),
                        fmaxf(pool[1][0][py][px][oc], pool[1][1][py][px][oc]));
        v += bias[oc];
        float a = slope[0];
        v = (v >= 0.f) ? v : a * v;
        P3[((long)n * 64 + oc) * 64 + zq * 16 + py * 4 + px] = v;
    }
}

// ---- conv3 (fp32 direct) ----
__global__ void conv3_kernel(const float* __restrict__ in,
                             const float* __restrict__ w,
                             const float* __restrict__ bias,
                             const float* __restrict__ slope,
                             float* __restrict__ out)
{
    int idx = blockIdx.x * blockDim.x + threadIdx.x;
    const int TOTAL = 80 * 64 * 8;
    if (idx >= TOTAL) return;
    int p  = idx & 7;
    int oc = (idx >> 3) & 63;
    int n  = idx >> 9;
    int ox = p & 1, oy = (p >> 1) & 1, oz = p >> 2;

    const float* inb = in + (long)n * 64 * 64;
    const float* wb  = w + (long)oc * 64 * 27;

    float acc = 0.f;
    for (int ic = 0; ic < 64; ++ic) {
        const float* inc = inb + ic * 64;
        const float* wc  = wb + ic * 27;
        #pragma unroll
        for (int kz = 0; kz < 3; ++kz)
            #pragma unroll
            for (int ky = 0; ky < 3; ++ky)
                #pragma unroll
                for (int kx = 0; kx < 3; ++kx)
                    acc += wc[(kz * 3 + ky) * 3 + kx] *
                           inc[((oz + kz) * 4 + (oy + ky)) * 4 + (ox + kx)];
    }
    float v = acc + bias[oc];
    float a = slope[0];
    v = (v >= 0.f) ? v : a * v;
    out[idx] = v;
}

// ---- comm-FC ----
template<int D, int O, bool PRELU_ON>
__global__ void comm_fc_kernel(const float* __restrict__ feat,
                               const float* __restrict__ w,
                               const float* __restrict__ bias,
                               const float* __restrict__ slope,
                               float* __restrict__ out)
{
    const int a = blockIdx.x;
    const int b = blockIdx.y;

    __shared__ __align__(16) float cat[2 * D];
    for (int i = threadIdx.x; i < D; i += blockDim.x) {
        float m = 0.f;
        #pragma unroll
        for (int aa = 0; aa < 5; ++aa) m += feat[(b * 5 + aa) * D + i];
        cat[i]     = feat[(b * 5 + a) * D + i];
        cat[D + i] = m * 0.2f;
    }
    __syncthreads();

    for (int o = threadIdx.x; o < O; o += blockDim.x) {
        const float4* wr = (const float4*)(w + ((long)(a * O) + o) * 2 * D);
        const float4* cr = (const float4*)cat;
        float acc = 0.f;
        for (int i = 0; i < 2 * D / 4; ++i) {
            float4 wv = wr[i];
            float4 cv = cr[i];
            acc += wv.x * cv.x + wv.y * cv.y + wv.z * cv.z + wv.w * cv.w;
        }
        acc += bias[a * O + o];
        if constexpr (PRELU_ON) {
            float s = slope[0];
            acc = (acc >= 0.f) ? acc : s * acc;
        }
        out[(b * 5 + a) * O + o] = acc;
    }
}

extern "C" void kernel_launch(void* const* d_in, const int* in_sizes, int n_in,
                              void* d_out, int out_size, void* d_ws, size_t ws_size,
                              hipStream_t stream)
{
    const float* x    = (const float*)d_in[0];
    const float* c0w  = (const float*)d_in[1];
    const float* c0b  = (const float*)d_in[2];
    const float* p0   = (const float*)d_in[3];
    const float* c1w  = (const float*)d_in[4];
    const float* c1b  = (const float*)d_in[5];
    const float* p1   = (const float*)d_in[6];
    const float* c2w  = (const float*)d_in[7];
    const float* c2b  = (const float*)d_in[8];
    const float* p2   = (const float*)d_in[9];
    const float* c3w  = (const float*)d_in[10];
    const float* c3b  = (const float*)d_in[11];
    const float* p3   = (const float*)d_in[12];
    const float* f1w  = (const float*)d_in[13];
    const float* f1b  = (const float*)d_in[14];
    const float* p4   = (const float*)d_in[15];
    const float* f2w  = (const float*)d_in[16];
    const float* f2b  = (const float*)d_in[17];
    const float* p5   = (const float*)d_in[18];
    const float* f3w  = (const float*)d_in[19];
    const float* f3b  = (const float*)d_in[20];

    char* ws = (char*)d_ws;
    ushort* hi0  = (ushort*)(ws);                         // 33,930,240 el f16
    ushort* hi1  = (ushort*)(ws + 67860480);              // 32,501,760 el f16
    ushort* P2h  = (ushort*)(ws + 132864000);             //  3,717,120 el f16
    ushort* P2l  = (ushort*)(ws + 140298240);             //  3,717,120 el f16
    float*  P3   = (float*) (ws + 147732480);             //    327,680 el
    float*  feat0= (float*) (ws + 149043200);
    float*  feat1= (float*) (ws + 149207040);
    float*  feat2= (float*) (ws + 149288960);
    ushort* Bp0  = (ushort*)(ws + 149329920);             // 19,456 el
    ushort* Bp1  = (ushort*)(ws + 149368832);             // 129,024 el
    int4*   Dt0  = (int4*)  (ws + 149626880);             // 19 (LDS deltas)
    ushort* Bp2h = (ushort*)(ws + 149700000);             // 131,072 el
    ushort* Bp2l = (ushort*)(ws + 149962144);             // 131,072 el
    int*    Dt2  = (int*)   (ws + 150224288);             // 64

    // zero halos of hi1 + all of P2h/P2l (hi0 halos written by pad_input now)
    hipMemsetAsync(ws + 67860480, 0, 79872000, stream);

    pack_w0<<<76, 256, 0, stream>>>(c0w, Bp0, Dt0);
    pack_w1<<<504, 256, 0, stream>>>(c1w, Bp1);
    pack_w2<<<512, 256, 0, stream>>>(c2w, Bp2h, Bp2l, Dt2);
    pad_input_kernel<<<(80 * 47 * 47 * 48 + 255) / 256, 256, 0, stream>>>(x, hi0);

    conv0_mfma<<<dim3(231, 1, 80), 256, 0, stream>>>(hi0, Bp0, Dt0,
                                                     c0b, p0, hi1);
    conv1_mfma<<<dim3(27, 1, 80), 256, 0, stream>>>(hi1, Bp1,
                                                    c1b, p1, P2h, P2l);
    conv2_mfma<<<dim3(320), 256, 0, stream>>>(P2h, P2l, Bp2h, Bp2l, Dt2,
                                              c2b, p2, P3);

    conv3_kernel<<<dim3(160), dim3(256), 0, stream>>>(P3, c3w, c3b, p3, feat0);

    comm_fc_kernel<512, 256, true>
        <<<dim3(5, 16), dim3(256), 0, stream>>>(feat0, f1w, f1b, p4, feat1);
    comm_fc_kernel<256, 128, true>
        <<<dim3(5, 16), dim3(256), 0, stream>>>(feat1, f2w, f2b, p5, feat2);
    comm_fc_kernel<128, 6, false>
        <<<dim3(5, 16), dim3(64), 0, stream>>>(feat2, f3w, f3b, nullptr, (float*)d_out);
}